// Round 1
// baseline (334.188 us; speedup 1.0000x reference)
//
#include <hip/hip_runtime.h>
#include <hip/hip_bf16.h>

typedef __attribute__((ext_vector_type(8))) short short8;
typedef __attribute__((ext_vector_type(4))) float f32x4;

#define HEADS 16
#define DH    64
#define LSEQ  512
#define CD    1024
#define BTN   16
#define MROWS (BTN * LSEQ)   /* 8192 */

static __device__ __forceinline__ unsigned short f2bf(float f) {
    union { float f; unsigned int u; } v; v.f = f;
    unsigned int u = v.u;
    u += 0x7fffu + ((u >> 16) & 1u);   // round-to-nearest-even
    return (unsigned short)(u >> 16);
}

// ---------------- Kernel 1: fused QKV projection + bias + l2norm ----------
// C[i][j] = sum_k x[i][k] * W'[j][k] + b'[j], W' = [wq ; wkv] (3072 x 1024)
// Epilogue: per-(row,head) l2 normalize over the 64-col head, store bf16:
//   q (scaled by 0.125) -> Qb[bth][l][d], k -> Kb[bth][l][d], v -> Vtb[bth][d][l]
__global__ __launch_bounds__(256)
void proj_qkv_kernel(const float* __restrict__ x,
                     const float* __restrict__ wq, const float* __restrict__ bq,
                     const float* __restrict__ wkv, const float* __restrict__ bkv,
                     unsigned short* __restrict__ Qb, unsigned short* __restrict__ Kb,
                     unsigned short* __restrict__ Vtb)
{
    __shared__ __attribute__((aligned(16))) unsigned short Asm[64 * 72];
    __shared__ __attribute__((aligned(16))) unsigned short Bsm[64 * 72];

    const int tid  = threadIdx.x;
    const int wv   = tid >> 6;
    const int lane = tid & 63;
    const int colw = lane & 15;
    const int grp  = lane >> 4;
    const int trow = tid >> 4;   // 0..15 (staging row within pass)
    const int tcol = tid & 15;   // 0..15 (staging float4 col)

    const int j0 = blockIdx.x * 64;   // output col tile in [0,3072)
    const int i0 = blockIdx.y * 64;   // row tile in [0,8192)

    const float* Wp; const float* bp;
    if (j0 < CD) { Wp = wq  + (size_t)j0 * CD;        bp = bq  + j0; }
    else         { Wp = wkv + (size_t)(j0 - CD) * CD; bp = bkv + (j0 - CD); }

    f32x4 acc[4] = {};

    for (int kt = 0; kt < CD; kt += 64) {
        #pragma unroll
        for (int p = 0; p < 4; ++p) {
            const int r = p * 16 + trow;
            const float4 va = *(const float4*)&x [(size_t)(i0 + r) * CD + kt + tcol * 4];
            const float4 vb = *(const float4*)&Wp[(size_t)r        * CD + kt + tcol * 4];
            union { unsigned short us[4]; unsigned long long u; } pa, pb;
            pa.us[0]=f2bf(va.x); pa.us[1]=f2bf(va.y); pa.us[2]=f2bf(va.z); pa.us[3]=f2bf(va.w);
            pb.us[0]=f2bf(vb.x); pb.us[1]=f2bf(vb.y); pb.us[2]=f2bf(vb.z); pb.us[3]=f2bf(vb.w);
            *(unsigned long long*)&Asm[r * 72 + tcol * 4] = pa.u;
            *(unsigned long long*)&Bsm[r * 72 + tcol * 4] = pb.u;
        }
        __syncthreads();
        #pragma unroll
        for (int ks = 0; ks < 2; ++ks) {
            const short8 a = *(const short8*)&Asm[(wv * 16 + colw) * 72 + ks * 32 + grp * 8];
            #pragma unroll
            for (int nb = 0; nb < 4; ++nb) {
                const short8 b = *(const short8*)&Bsm[(nb * 16 + colw) * 72 + ks * 32 + grp * 8];
                acc[nb] = __builtin_amdgcn_mfma_f32_16x16x32_bf16(a, b, acc[nb], 0, 0, 0);
            }
        }
        __syncthreads();
    }

    // ---- epilogue: bias, l2norm over the 64-col head, store ----
    #pragma unroll
    for (int nb = 0; nb < 4; ++nb) {
        const float bv = bp[nb * 16 + colw];
        #pragma unroll
        for (int r = 0; r < 4; ++r) acc[nb][r] += bv;
    }
    float s[4];
    #pragma unroll
    for (int r = 0; r < 4; ++r) {
        float t = 0.f;
        #pragma unroll
        for (int nb = 0; nb < 4; ++nb) t += acc[nb][r] * acc[nb][r];
        s[r] = t;
    }
    #pragma unroll
    for (int r = 0; r < 4; ++r) {
        s[r] += __shfl_xor(s[r], 1);
        s[r] += __shfl_xor(s[r], 2);
        s[r] += __shfl_xor(s[r], 4);
        s[r] += __shfl_xor(s[r], 8);
    }
    float inv[4];
    const float qscale = (j0 < CD) ? 0.125f : 1.0f;   // fold 1/sqrt(D) into q
    #pragma unroll
    for (int r = 0; r < 4; ++r)
        inv[r] = qscale / fmaxf(sqrtf(s[r]), 1e-12f);

    #pragma unroll
    for (int nb = 0; nb < 4; ++nb) {
        #pragma unroll
        for (int r = 0; r < 4; ++r) {
            const int i = i0 + wv * 16 + grp * 4 + r;
            const int j = j0 + nb * 16 + colw;
            const unsigned short hv = f2bf(acc[nb][r] * inv[r]);
            const int bt = i >> 9, li = i & 511;
            if (j < CD) {
                const int h = j >> 6, d = j & 63;
                Qb[(((size_t)(bt * HEADS + h)) * LSEQ + li) * DH + d] = hv;
            } else if (j < 2 * CD) {
                const int jk = j - CD, h = jk >> 6, d = jk & 63;
                Kb[(((size_t)(bt * HEADS + h)) * LSEQ + li) * DH + d] = hv;
            } else {
                const int jv = j - 2 * CD, h = jv >> 6, d = jv & 63;
                Vtb[(((size_t)(bt * HEADS + h)) * DH + d) * LSEQ + li] = hv;
            }
        }
    }
}

// ---------------- Kernel 2: flash attention per (b,t,h) ----------
// block = 4 waves; each wave owns 16 q-rows; KV tile = 32
__global__ __launch_bounds__(256)
void attn_kernel(const unsigned short* __restrict__ Qb,
                 const unsigned short* __restrict__ Kb,
                 const unsigned short* __restrict__ Vtb,
                 unsigned short* __restrict__ Ob)
{
    __shared__ __attribute__((aligned(16))) unsigned short Psm[4][16 * 40];

    const int tid  = threadIdx.x;
    const int wv   = tid >> 6;
    const int lane = tid & 63;
    const int colw = lane & 15;
    const int grp  = lane >> 4;

    const int bth = blockIdx.x >> 3;      // 0..255
    const int qt  = blockIdx.x & 7;
    const int q0  = qt * 64 + wv * 16;    // wave's first q row

    const unsigned short* Qh = Qb  + (size_t)bth * LSEQ * DH;
    const unsigned short* Kh = Kb  + (size_t)bth * LSEQ * DH;
    const unsigned short* Vh = Vtb + (size_t)bth * DH * LSEQ;

    short8 aq[2];
    #pragma unroll
    for (int ks = 0; ks < 2; ++ks)
        aq[ks] = *(const short8*)&Qh[(size_t)(q0 + colw) * DH + ks * 32 + grp * 8];

    float m[4], lsum[4];
    f32x4 oacc[4] = {};
    #pragma unroll
    for (int r = 0; r < 4; ++r) { m[r] = -INFINITY; lsum[r] = 0.f; }

    for (int kv0 = 0; kv0 < LSEQ; kv0 += 32) {
        f32x4 s0 = {}, s1 = {};
        #pragma unroll
        for (int ks = 0; ks < 2; ++ks) {
            const short8 b0 = *(const short8*)&Kh[(size_t)(kv0 + colw) * DH + ks * 32 + grp * 8];
            const short8 b1 = *(const short8*)&Kh[(size_t)(kv0 + 16 + colw) * DH + ks * 32 + grp * 8];
            s0 = __builtin_amdgcn_mfma_f32_16x16x32_bf16(aq[ks], b0, s0, 0, 0, 0);
            s1 = __builtin_amdgcn_mfma_f32_16x16x32_bf16(aq[ks], b1, s1, 0, 0, 0);
        }
        float mn[4], corr[4];
        #pragma unroll
        for (int r = 0; r < 4; ++r) {
            float t = fmaxf(s0[r], s1[r]);
            t = fmaxf(t, __shfl_xor(t, 1));
            t = fmaxf(t, __shfl_xor(t, 2));
            t = fmaxf(t, __shfl_xor(t, 4));
            t = fmaxf(t, __shfl_xor(t, 8));
            mn[r]   = fmaxf(m[r], t);
            corr[r] = __expf(m[r] - mn[r]);
            m[r]    = mn[r];
        }
        float p0[4], p1[4];
        #pragma unroll
        for (int r = 0; r < 4; ++r) {
            p0[r] = __expf(s0[r] - mn[r]);
            p1[r] = __expf(s1[r] - mn[r]);
            float t = p0[r] + p1[r];
            t += __shfl_xor(t, 1);
            t += __shfl_xor(t, 2);
            t += __shfl_xor(t, 4);
            t += __shfl_xor(t, 8);
            lsum[r] = lsum[r] * corr[r] + t;
        }
        #pragma unroll
        for (int nd = 0; nd < 4; ++nd)
            #pragma unroll
            for (int r = 0; r < 4; ++r) oacc[nd][r] *= corr[r];

        // P (C-layout) -> LDS -> A-layout fragments
        #pragma unroll
        for (int r = 0; r < 4; ++r) {
            Psm[wv][(grp * 4 + r) * 40 + colw]      = f2bf(p0[r]);
            Psm[wv][(grp * 4 + r) * 40 + 16 + colw] = f2bf(p1[r]);
        }
        const short8 ap = *(const short8*)&Psm[wv][colw * 40 + grp * 8];
        #pragma unroll
        for (int nd = 0; nd < 4; ++nd) {
            const short8 bvv = *(const short8*)&Vh[(size_t)(nd * 16 + colw) * LSEQ + kv0 + grp * 8];
            oacc[nd] = __builtin_amdgcn_mfma_f32_16x16x32_bf16(ap, bvv, oacc[nd], 0, 0, 0);
        }
    }

    const int bt = bth >> 4, h = bth & 15;
    #pragma unroll
    for (int nd = 0; nd < 4; ++nd) {
        #pragma unroll
        for (int r = 0; r < 4; ++r) {
            const int i = bt * LSEQ + q0 + grp * 4 + r;
            const int c = h * 64 + nd * 16 + colw;
            Ob[(size_t)i * CD + c] = f2bf(oacc[nd][r] / lsum[r]);
        }
    }
}

// ---------------- Kernel 3: output projection + bias + residual ----------
__global__ __launch_bounds__(256)
void proj_out_kernel(const unsigned short* __restrict__ Ob,
                     const float* __restrict__ wm, const float* __restrict__ bm,
                     const float* __restrict__ x, float* __restrict__ out)
{
    __shared__ __attribute__((aligned(16))) unsigned short Asm[64 * 72];
    __shared__ __attribute__((aligned(16))) unsigned short Bsm[64 * 72];

    const int tid  = threadIdx.x;
    const int wv   = tid >> 6;
    const int lane = tid & 63;
    const int colw = lane & 15;
    const int grp  = lane >> 4;
    const int trow = tid >> 4;
    const int tcol = tid & 15;

    const int j0 = blockIdx.x * 64;
    const int i0 = blockIdx.y * 64;

    f32x4 acc[4] = {};

    for (int kt = 0; kt < CD; kt += 64) {
        #pragma unroll
        for (int p = 0; p < 4; ++p) {
            const int r = p * 16 + trow;
            const unsigned long long va =
                *(const unsigned long long*)&Ob[(size_t)(i0 + r) * CD + kt + tcol * 4];
            *(unsigned long long*)&Asm[r * 72 + tcol * 4] = va;
            const float4 vb = *(const float4*)&wm[(size_t)(j0 + r) * CD + kt + tcol * 4];
            union { unsigned short us[4]; unsigned long long u; } pb;
            pb.us[0]=f2bf(vb.x); pb.us[1]=f2bf(vb.y); pb.us[2]=f2bf(vb.z); pb.us[3]=f2bf(vb.w);
            *(unsigned long long*)&Bsm[r * 72 + tcol * 4] = pb.u;
        }
        __syncthreads();
        #pragma unroll
        for (int ks = 0; ks < 2; ++ks) {
            const short8 a = *(const short8*)&Asm[(wv * 16 + colw) * 72 + ks * 32 + grp * 8];
            #pragma unroll
            for (int nb = 0; nb < 4; ++nb) {
                const short8 b = *(const short8*)&Bsm[(nb * 16 + colw) * 72 + ks * 32 + grp * 8];
                acc[nb] = __builtin_amdgcn_mfma_f32_16x16x32_bf16(a, b, acc[nb], 0, 0, 0);
            }
        }
        __syncthreads();
    }

    #pragma unroll
    for (int nb = 0; nb < 4; ++nb) {
        const float bv = bm[j0 + nb * 16 + colw];
        #pragma unroll
        for (int r = 0; r < 4; ++r) {
            const int i = i0 + wv * 16 + grp * 4 + r;
            const int j = j0 + nb * 16 + colw;
            out[(size_t)i * CD + j] = acc[nb][r] + bv + x[(size_t)i * CD + j];
        }
    }
}

extern "C" void kernel_launch(void* const* d_in, const int* in_sizes, int n_in,
                              void* d_out, int out_size, void* d_ws, size_t ws_size,
                              hipStream_t stream) {
    const float* x   = (const float*)d_in[0];
    const float* wq  = (const float*)d_in[1];
    const float* bq  = (const float*)d_in[2];
    const float* wkv = (const float*)d_in[3];
    const float* bkv = (const float*)d_in[4];
    const float* wm  = (const float*)d_in[5];
    const float* bm  = (const float*)d_in[6];
    float* out = (float*)d_out;

    unsigned short* Qb  = (unsigned short*)d_ws;                 // 8192*1024 bf16
    unsigned short* Kb  = Qb  + (size_t)MROWS * CD;
    unsigned short* Vtb = Kb  + (size_t)MROWS * CD;
    unsigned short* Ob  = Vtb + (size_t)MROWS * CD;              // total 64 MB

    proj_qkv_kernel<<<dim3(48, 128), 256, 0, stream>>>(x, wq, bq, wkv, bkv, Qb, Kb, Vtb);
    attn_kernel<<<2048, 256, 0, stream>>>(Qb, Kb, Vtb, Ob);
    proj_out_kernel<<<dim3(16, 128), 256, 0, stream>>>(Ob, wm, bm, x, out);
}

// Round 2
// 280.492 us; speedup vs baseline: 1.1914x; 1.1914x over previous
//
#include <hip/hip_runtime.h>
#include <hip/hip_bf16.h>

typedef __attribute__((ext_vector_type(8))) short short8;
typedef __attribute__((ext_vector_type(4))) float f32x4;

#define HEADS 16
#define DH    64
#define LSEQ  512
#define CD    1024
#define MROWS 8192            /* B*T*L */
#define NQKV  3072

static __device__ __forceinline__ unsigned short f2bf(float f) {
    union { float f; unsigned int u; } v; v.f = f;
    unsigned int u = v.u;
    u += 0x7fffu + ((u >> 16) & 1u);   // round-to-nearest-even
    return (unsigned short)(u >> 16);
}

static __device__ __forceinline__ void gload16(const unsigned short* g, unsigned short* lds) {
    __builtin_amdgcn_global_load_lds(
        (const __attribute__((address_space(1))) void*)g,
        (__attribute__((address_space(3))) void*)lds, 16, 0, 0);
}

// ---------------- f32 -> bf16 bulk convert (vec4) ----------------
__global__ __launch_bounds__(256)
void cvt_kernel(const float* __restrict__ s, unsigned short* __restrict__ d, int n4) {
    union U { unsigned short us[4]; unsigned long long u; };
    for (int i = blockIdx.x * blockDim.x + threadIdx.x; i < n4; i += gridDim.x * blockDim.x) {
        const float4 v = ((const float4*)s)[i];
        U p; p.us[0] = f2bf(v.x); p.us[1] = f2bf(v.y); p.us[2] = f2bf(v.z); p.us[3] = f2bf(v.w);
        ((unsigned long long*)d)[i] = p.u;
    }
}

// ---------------- Kernel 1: fused QKV projection (m97 structure) ----------
// 128x128 tile, BK=64, 4 waves (2x2), 4x4 16x16x32 fragments per wave.
// Epilogue: bias + per-(row,head) l2norm; q scaled by 0.125; V stored transposed.
__global__ __launch_bounds__(256)
void proj_qkv_kernel(const unsigned short* __restrict__ xb,
                     const unsigned short* __restrict__ wqkvb,
                     const float* __restrict__ bq, const float* __restrict__ bkv,
                     unsigned short* __restrict__ Qb, unsigned short* __restrict__ Kb,
                     unsigned short* __restrict__ Vtb)
{
    __shared__ __attribute__((aligned(16))) unsigned short Asm[128 * 64];
    __shared__ __attribute__((aligned(16))) unsigned short Bsm[128 * 64];

    const int tid  = threadIdx.x;
    const int wv   = tid >> 6;
    const int lane = tid & 63;
    const int colw = lane & 15;
    const int grp  = lane >> 4;
    const int wr   = wv >> 1;
    const int wc   = wv & 1;
    const int lr   = lane >> 3;   // 0..7 row within 8-row chunk
    const int lc   = lane & 7;    // 0..7 16B col within 128B row

    const int j0 = blockIdx.x * 128;   // output col tile in [0,3072)
    const int i0 = blockIdx.y * 128;   // row tile in [0,8192)

    const unsigned short* Ap = xb    + (size_t)i0 * CD;
    const unsigned short* Bp = wqkvb + (size_t)j0 * CD;

    f32x4 acc[4][4] = {};

    for (int kt = 0; kt < CD; kt += 64) {
        #pragma unroll
        for (int c = 0; c < 4; ++c) {
            const int row = wv * 32 + c * 8;
            gload16(Ap + (size_t)(row + lr) * CD + kt + lc * 8, &Asm[row * 64]);
            gload16(Bp + (size_t)(row + lr) * CD + kt + lc * 8, &Bsm[row * 64]);
        }
        __syncthreads();
        #pragma unroll
        for (int ks = 0; ks < 2; ++ks) {
            short8 af[4], bf[4];
            #pragma unroll
            for (int mf = 0; mf < 4; ++mf)
                af[mf] = *(const short8*)&Asm[(wr * 64 + mf * 16 + colw) * 64 + ks * 32 + grp * 8];
            #pragma unroll
            for (int nf = 0; nf < 4; ++nf)
                bf[nf] = *(const short8*)&Bsm[(wc * 64 + nf * 16 + colw) * 64 + ks * 32 + grp * 8];
            #pragma unroll
            for (int mf = 0; mf < 4; ++mf)
                #pragma unroll
                for (int nf = 0; nf < 4; ++nf)
                    acc[mf][nf] = __builtin_amdgcn_mfma_f32_16x16x32_bf16(af[mf], bf[nf], acc[mf][nf], 0, 0, 0);
        }
        __syncthreads();
    }

    // ---- epilogue ----
    const int jbase = j0 + wc * 64;                      // head-aligned 64-col span
    const float* bp = (j0 < CD) ? (bq + jbase) : (bkv + (jbase - CD));
    #pragma unroll
    for (int nf = 0; nf < 4; ++nf) {
        const float bv = bp[nf * 16 + colw];
        #pragma unroll
        for (int mf = 0; mf < 4; ++mf)
            #pragma unroll
            for (int r = 0; r < 4; ++r) acc[mf][nf][r] += bv;
    }
    const float qscale = (jbase < CD) ? 0.125f : 1.0f;   // fold 1/sqrt(D) into q
    float inv[4][4];
    #pragma unroll
    for (int mf = 0; mf < 4; ++mf) {
        #pragma unroll
        for (int r = 0; r < 4; ++r) {
            float t = 0.f;
            #pragma unroll
            for (int nf = 0; nf < 4; ++nf) t += acc[mf][nf][r] * acc[mf][nf][r];
            t += __shfl_xor(t, 1);
            t += __shfl_xor(t, 2);
            t += __shfl_xor(t, 4);
            t += __shfl_xor(t, 8);
            inv[mf][r] = qscale / fmaxf(sqrtf(t), 1e-12f);
        }
    }
    #pragma unroll
    for (int mf = 0; mf < 4; ++mf) {
        #pragma unroll
        for (int nf = 0; nf < 4; ++nf) {
            #pragma unroll
            for (int r = 0; r < 4; ++r) {
                const int i = i0 + wr * 64 + mf * 16 + grp * 4 + r;
                const int j = jbase + nf * 16 + colw;
                const unsigned short hv = f2bf(acc[mf][nf][r] * inv[mf][r]);
                const int bt = i >> 9, li = i & 511;
                if (j < CD) {
                    const int h = j >> 6, d = j & 63;
                    Qb[(((size_t)(bt * HEADS + h)) * LSEQ + li) * DH + d] = hv;
                } else if (j < 2 * CD) {
                    const int jk = j - CD, h = jk >> 6, d = jk & 63;
                    Kb[(((size_t)(bt * HEADS + h)) * LSEQ + li) * DH + d] = hv;
                } else {
                    const int jv = j - 2 * CD, h = jv >> 6, d = jv & 63;
                    Vtb[(((size_t)(bt * HEADS + h)) * DH + d) * LSEQ + li] = hv;
                }
            }
        }
    }
}

// ---------------- Kernel 2: flash attention per (b,t,h) ----------
__global__ __launch_bounds__(256)
void attn_kernel(const unsigned short* __restrict__ Qb,
                 const unsigned short* __restrict__ Kb,
                 const unsigned short* __restrict__ Vtb,
                 unsigned short* __restrict__ Ob)
{
    __shared__ __attribute__((aligned(16))) unsigned short Psm[4][16 * 40];

    const int tid  = threadIdx.x;
    const int wv   = tid >> 6;
    const int lane = tid & 63;
    const int colw = lane & 15;
    const int grp  = lane >> 4;

    const int bth = blockIdx.x >> 3;      // 0..255
    const int qt  = blockIdx.x & 7;
    const int q0  = qt * 64 + wv * 16;    // wave's first q row

    const unsigned short* Qh = Qb  + (size_t)bth * LSEQ * DH;
    const unsigned short* Kh = Kb  + (size_t)bth * LSEQ * DH;
    const unsigned short* Vh = Vtb + (size_t)bth * DH * LSEQ;

    short8 aq[2];
    #pragma unroll
    for (int ks = 0; ks < 2; ++ks)
        aq[ks] = *(const short8*)&Qh[(size_t)(q0 + colw) * DH + ks * 32 + grp * 8];

    float m[4], lsum[4];
    f32x4 oacc[4] = {};
    #pragma unroll
    for (int r = 0; r < 4; ++r) { m[r] = -INFINITY; lsum[r] = 0.f; }

    for (int kv0 = 0; kv0 < LSEQ; kv0 += 32) {
        f32x4 s0 = {}, s1 = {};
        #pragma unroll
        for (int ks = 0; ks < 2; ++ks) {
            const short8 b0 = *(const short8*)&Kh[(size_t)(kv0 + colw) * DH + ks * 32 + grp * 8];
            const short8 b1 = *(const short8*)&Kh[(size_t)(kv0 + 16 + colw) * DH + ks * 32 + grp * 8];
            s0 = __builtin_amdgcn_mfma_f32_16x16x32_bf16(aq[ks], b0, s0, 0, 0, 0);
            s1 = __builtin_amdgcn_mfma_f32_16x16x32_bf16(aq[ks], b1, s1, 0, 0, 0);
        }
        float mn[4], corr[4];
        #pragma unroll
        for (int r = 0; r < 4; ++r) {
            float t = fmaxf(s0[r], s1[r]);
            t = fmaxf(t, __shfl_xor(t, 1));
            t = fmaxf(t, __shfl_xor(t, 2));
            t = fmaxf(t, __shfl_xor(t, 4));
            t = fmaxf(t, __shfl_xor(t, 8));
            mn[r]   = fmaxf(m[r], t);
            corr[r] = __expf(m[r] - mn[r]);
            m[r]    = mn[r];
        }
        float p0[4], p1[4];
        #pragma unroll
        for (int r = 0; r < 4; ++r) {
            p0[r] = __expf(s0[r] - mn[r]);
            p1[r] = __expf(s1[r] - mn[r]);
            float t = p0[r] + p1[r];
            t += __shfl_xor(t, 1);
            t += __shfl_xor(t, 2);
            t += __shfl_xor(t, 4);
            t += __shfl_xor(t, 8);
            lsum[r] = lsum[r] * corr[r] + t;
        }
        #pragma unroll
        for (int nd = 0; nd < 4; ++nd)
            #pragma unroll
            for (int r = 0; r < 4; ++r) oacc[nd][r] *= corr[r];

        // P (C-layout) -> LDS -> A-layout fragments
        #pragma unroll
        for (int r = 0; r < 4; ++r) {
            Psm[wv][(grp * 4 + r) * 40 + colw]      = f2bf(p0[r]);
            Psm[wv][(grp * 4 + r) * 40 + 16 + colw] = f2bf(p1[r]);
        }
        const short8 ap = *(const short8*)&Psm[wv][colw * 40 + grp * 8];
        #pragma unroll
        for (int nd = 0; nd < 4; ++nd) {
            const short8 bvv = *(const short8*)&Vh[(size_t)(nd * 16 + colw) * LSEQ + kv0 + grp * 8];
            oacc[nd] = __builtin_amdgcn_mfma_f32_16x16x32_bf16(ap, bvv, oacc[nd], 0, 0, 0);
        }
    }

    const int bt = bth >> 4, h = bth & 15;
    #pragma unroll
    for (int nd = 0; nd < 4; ++nd) {
        #pragma unroll
        for (int r = 0; r < 4; ++r) {
            const int i = bt * LSEQ + q0 + grp * 4 + r;
            const int c = h * 64 + nd * 16 + colw;
            Ob[(size_t)i * CD + c] = f2bf(oacc[nd][r] / lsum[r]);
        }
    }
}

// ---------------- Kernel 3: output projection + bias + residual ----------
__global__ __launch_bounds__(256)
void proj_out_kernel(const unsigned short* __restrict__ Ob,
                     const unsigned short* __restrict__ wmb,
                     const float* __restrict__ bm,
                     const float* __restrict__ x, float* __restrict__ out)
{
    __shared__ __attribute__((aligned(16))) unsigned short Asm[128 * 64];
    __shared__ __attribute__((aligned(16))) unsigned short Bsm[128 * 64];

    const int tid  = threadIdx.x;
    const int wv   = tid >> 6;
    const int lane = tid & 63;
    const int colw = lane & 15;
    const int grp  = lane >> 4;
    const int wr   = wv >> 1;
    const int wc   = wv & 1;
    const int lr   = lane >> 3;
    const int lc   = lane & 7;

    const int j0 = blockIdx.x * 128;
    const int i0 = blockIdx.y * 128;

    const unsigned short* Ap = Ob  + (size_t)i0 * CD;
    const unsigned short* Bp = wmb + (size_t)j0 * CD;

    f32x4 acc[4][4] = {};

    for (int kt = 0; kt < CD; kt += 64) {
        #pragma unroll
        for (int c = 0; c < 4; ++c) {
            const int row = wv * 32 + c * 8;
            gload16(Ap + (size_t)(row + lr) * CD + kt + lc * 8, &Asm[row * 64]);
            gload16(Bp + (size_t)(row + lr) * CD + kt + lc * 8, &Bsm[row * 64]);
        }
        __syncthreads();
        #pragma unroll
        for (int ks = 0; ks < 2; ++ks) {
            short8 af[4], bf[4];
            #pragma unroll
            for (int mf = 0; mf < 4; ++mf)
                af[mf] = *(const short8*)&Asm[(wr * 64 + mf * 16 + colw) * 64 + ks * 32 + grp * 8];
            #pragma unroll
            for (int nf = 0; nf < 4; ++nf)
                bf[nf] = *(const short8*)&Bsm[(wc * 64 + nf * 16 + colw) * 64 + ks * 32 + grp * 8];
            #pragma unroll
            for (int mf = 0; mf < 4; ++mf)
                #pragma unroll
                for (int nf = 0; nf < 4; ++nf)
                    acc[mf][nf] = __builtin_amdgcn_mfma_f32_16x16x32_bf16(af[mf], bf[nf], acc[mf][nf], 0, 0, 0);
        }
        __syncthreads();
    }

    #pragma unroll
    for (int nf = 0; nf < 4; ++nf) {
        const int j = j0 + wc * 64 + nf * 16 + colw;
        const float bv = bm[j];
        #pragma unroll
        for (int mf = 0; mf < 4; ++mf) {
            #pragma unroll
            for (int r = 0; r < 4; ++r) {
                const int i = i0 + wr * 64 + mf * 16 + grp * 4 + r;
                out[(size_t)i * CD + j] = acc[mf][nf][r] + bv + x[(size_t)i * CD + j];
            }
        }
    }
}

extern "C" void kernel_launch(void* const* d_in, const int* in_sizes, int n_in,
                              void* d_out, int out_size, void* d_ws, size_t ws_size,
                              hipStream_t stream) {
    const float* x   = (const float*)d_in[0];
    const float* wq  = (const float*)d_in[1];
    const float* bq  = (const float*)d_in[2];
    const float* wkv = (const float*)d_in[3];
    const float* bkv = (const float*)d_in[4];
    const float* wm  = (const float*)d_in[5];
    const float* bm  = (const float*)d_in[6];
    float* out = (float*)d_out;

    // ws layout (64 MB, timeline-aliased):
    //  R0: xb (convert->proj_qkv), then Ob (attn->proj_out)
    //  R1: Qb (proj_qkv->attn), then wmb (cvt-after-attn->proj_out)
    //  R2: Kb   R3: Vtb
    // wqkvb lives in d_out (dead before proj_out writes d_out).
    const size_t SEG = (size_t)MROWS * CD;            // 8.39M elems = 16 MB bf16
    unsigned short* xb    = (unsigned short*)d_ws;
    unsigned short* Ob    = xb;                       // alias (xb dead after proj_qkv)
    unsigned short* Qb    = xb + SEG;
    unsigned short* wmb   = Qb;                       // alias (Qb dead after attn)
    unsigned short* Kb    = Qb + SEG;
    unsigned short* Vtb   = Kb + SEG;
    unsigned short* wqkvb = (unsigned short*)d_out;   // scratch in d_out (6.3 MB)

    cvt_kernel<<<2048, 256, 0, stream>>>(x,   xb,    (MROWS * CD) / 4);
    cvt_kernel<<<1024, 256, 0, stream>>>(wq,  wqkvb, (CD * CD) / 4);
    cvt_kernel<<<1024, 256, 0, stream>>>(wkv, wqkvb + (size_t)CD * CD, (2 * CD * CD) / 4);
    proj_qkv_kernel<<<dim3(24, 64), 256, 0, stream>>>(xb, wqkvb, bq, bkv, Qb, Kb, Vtb);
    attn_kernel<<<2048, 256, 0, stream>>>(Qb, Kb, Vtb, Ob);
    cvt_kernel<<<1024, 256, 0, stream>>>(wm, wmb, (CD * CD) / 4);
    proj_out_kernel<<<dim3(8, 64), 256, 0, stream>>>(Ob, wmb, bm, x, out);
}

// Round 3
// 269.329 us; speedup vs baseline: 1.2408x; 1.0414x over previous
//
#include <hip/hip_runtime.h>
#include <hip/hip_bf16.h>

typedef __attribute__((ext_vector_type(8))) short short8;
typedef __attribute__((ext_vector_type(4))) float f32x4;

#define HEADS 16
#define DH    64
#define LSEQ  512
#define CD    1024
#define MROWS 8192            /* B*T*L */

static __device__ __forceinline__ unsigned short f2bf(float f) {
    union { float f; unsigned int u; } v; v.f = f;
    unsigned int u = v.u;
    u += 0x7fffu + ((u >> 16) & 1u);   // round-to-nearest-even
    return (unsigned short)(u >> 16);
}

static __device__ __forceinline__ void gload16(const unsigned short* g, char* lds) {
    __builtin_amdgcn_global_load_lds(
        (const __attribute__((address_space(1))) void*)g,
        (__attribute__((address_space(3))) void*)lds, 16, 0, 0);
}

// ---------------- f32 -> bf16 bulk convert (vec4) ----------------
__global__ __launch_bounds__(256)
void cvt_kernel(const float* __restrict__ s, unsigned short* __restrict__ d, int n4) {
    union U { unsigned short us[4]; unsigned long long u; };
    for (int i = blockIdx.x * blockDim.x + threadIdx.x; i < n4; i += gridDim.x * blockDim.x) {
        const float4 v = ((const float4*)s)[i];
        U p; p.us[0] = f2bf(v.x); p.us[1] = f2bf(v.y); p.us[2] = f2bf(v.z); p.us[3] = f2bf(v.w);
        ((unsigned long long*)d)[i] = p.u;
    }
}

// ================= multi-phase GEMM core (T3+T4+T2+T5) =================
// BM=128, BN=256, BK=32, 8 waves (2M x 4N), ring-4 LDS (24 KB/slot = 96 KB).
// LDS slot: A = 64 rows x 128B (paired tile-rows, 8KB) at +0
//           B = 128 rows x 128B (paired tile-rows, 16KB) at +8192
// Swizzle: 16B-chunk index within 128B row XOR'ed with (ldsrow & 7);
// applied on the per-lane GLOBAL source (stage) and on ds_read (read).
#define SLOT_BYTES (24 * 1024)

static __device__ __forceinline__ void gemm_core(
    const unsigned short* __restrict__ Ap,   // [M][CD] bf16
    const unsigned short* __restrict__ Bp,   // [N][CD] bf16
    int i0, int n0, char* lds, f32x4 acc[4][4])
{
    const int tid  = threadIdx.x;
    const int w    = tid >> 6;        // 0..7
    const int lane = tid & 63;
    const int colw = lane & 15;
    const int grp  = lane >> 4;
    const int wm   = w >> 2;          // 0..1
    const int wn   = w & 3;           // 0..3

    // ---- staging constants (per-lane pre-swizzled global source) ----
    const int cl   = (lane & 7) ^ (lane >> 3);   // logical chunk (phys chunk = lane&7)
    const int bsel = cl >> 2;                    // tile-row parity within LDS row
    const int kc   = (cl & 3) * 8;               // element offset within 32-col K slice
    const int arow = 2 * (w * 8  + (lane >> 3)) + bsel;   // 0..127
    const int brow = 2 * (w * 16 + (lane >> 3)) + bsel;   // s=0 row; s=1 adds 16
    const unsigned short* Ag  = Ap + (size_t)(i0 + arow) * CD + kc;
    const unsigned short* Bg0 = Bp + (size_t)(n0 + brow) * CD + kc;
    const unsigned short* Bg1 = Bp + (size_t)(n0 + brow + 16) * CD + kc;
    char* const adst  = lds + w * 8 * 128;
    char* const bdst0 = lds + 8192 + w * 16 * 128;
    char* const bdst1 = bdst0 + 8 * 128;

    // ---- fragment ds_read byte offsets (swizzled) ----
    int aoff[4], boff[4];
    #pragma unroll
    for (int mf = 0; mf < 4; ++mf) {
        const int rr = wm * 64 + mf * 16 + colw;
        aoff[mf] = (rr >> 1) * 128 + (((((rr & 1) << 2) | grp) ^ ((rr >> 1) & 7)) << 4);
    }
    #pragma unroll
    for (int nf = 0; nf < 4; ++nf) {
        const int rr = wn * 64 + nf * 16 + colw;
        boff[nf] = 8192 + (rr >> 1) * 128 + (((((rr & 1) << 2) | grp) ^ ((rr >> 1) & 7)) << 4);
    }

    const int NT = CD / 32;   // 32 K-tiles

    // ---- prologue: stage tiles 0,1,2 ----
    #pragma unroll
    for (int t = 0; t < 3; ++t) {
        char* sb = lds + t * SLOT_BYTES;
        gload16(Ag  + t * 32, sb + (adst  - lds));
        gload16(Bg0 + t * 32, sb + (bdst0 - lds));
        gload16(Bg1 + t * 32, sb + (bdst1 - lds));
    }
    asm volatile("s_waitcnt vmcnt(6)" ::: "memory");
    __builtin_amdgcn_sched_barrier(0);
    __builtin_amdgcn_s_barrier();

    #pragma unroll 4
    for (int t = 0; t < NT; ++t) {
        const char* sb = lds + (t & 3) * SLOT_BYTES;
        short8 af[4], bf[4];
        #pragma unroll
        for (int mf = 0; mf < 4; ++mf) af[mf] = *(const short8*)(sb + aoff[mf]);
        #pragma unroll
        for (int nf = 0; nf < 4; ++nf) bf[nf] = *(const short8*)(sb + boff[nf]);

        // stage tile t+3 (clamped tail: redundant re-stage into a dead slot)
        const int tn = (t + 3 < NT) ? t + 3 : NT - 1;
        char* db = lds + ((t + 3) & 3) * SLOT_BYTES;
        gload16(Ag  + tn * 32, db + (adst  - lds));
        gload16(Bg0 + tn * 32, db + (bdst0 - lds));
        gload16(Bg1 + tn * 32, db + (bdst1 - lds));

        __builtin_amdgcn_s_setprio(1);
        #pragma unroll
        for (int nf = 0; nf < 4; ++nf)
            #pragma unroll
            for (int mf = 0; mf < 4; ++mf)
                acc[mf][nf] = __builtin_amdgcn_mfma_f32_16x16x32_bf16(af[mf], bf[nf], acc[mf][nf], 0, 0, 0);
        __builtin_amdgcn_s_setprio(0);

        asm volatile("s_waitcnt vmcnt(6)" ::: "memory");   // gate: tile t+1 fully staged
        __builtin_amdgcn_sched_barrier(0);
        __builtin_amdgcn_s_barrier();
    }
}

// ---------------- Kernel 1: fused QKV projection ----------
__global__ __launch_bounds__(512, 2)
void proj_qkv_kernel(const unsigned short* __restrict__ xb,
                     const unsigned short* __restrict__ wqkvb,
                     const float* __restrict__ bq, const float* __restrict__ bkv,
                     unsigned short* __restrict__ Qb, unsigned short* __restrict__ Kb,
                     unsigned short* __restrict__ Vtb)
{
    __shared__ __attribute__((aligned(16))) char lds[96 * 1024];

    // grid = 768 (64 m-tiles x 12 n-tiles), bijective XCD swizzle (nwg%8==0)
    const int wg   = (blockIdx.x & 7) * 96 + (blockIdx.x >> 3);
    const int in_t = wg / 64, im_t = wg % 64;
    const int i0 = im_t * 128, n0 = in_t * 256;

    const int tid  = threadIdx.x;
    const int w    = tid >> 6;
    const int lane = tid & 63;
    const int colw = lane & 15;
    const int grp  = lane >> 4;
    const int wm   = w >> 2, wn = w & 3;

    f32x4 acc[4][4] = {};
    gemm_core(xb, wqkvb, i0, n0, lds, acc);

    // ---- epilogue: bias + l2norm over 64-col head; scatter store ----
    const int jbase = n0 + wn * 64;               // head-aligned, wave-uniform
    const float* bp = (jbase < CD) ? (bq + jbase) : (bkv + (jbase - CD));
    #pragma unroll
    for (int nf = 0; nf < 4; ++nf) {
        const float bv = bp[nf * 16 + colw];
        #pragma unroll
        for (int mf = 0; mf < 4; ++mf)
            #pragma unroll
            for (int r = 0; r < 4; ++r) acc[mf][nf][r] += bv;
    }
    const float qscale = (jbase < CD) ? 0.125f : 1.0f;
    float inv[4][4];
    #pragma unroll
    for (int mf = 0; mf < 4; ++mf) {
        #pragma unroll
        for (int r = 0; r < 4; ++r) {
            float t = 0.f;
            #pragma unroll
            for (int nf = 0; nf < 4; ++nf) t += acc[mf][nf][r] * acc[mf][nf][r];
            t += __shfl_xor(t, 1);
            t += __shfl_xor(t, 2);
            t += __shfl_xor(t, 4);
            t += __shfl_xor(t, 8);
            inv[mf][r] = qscale / fmaxf(sqrtf(t), 1e-12f);
        }
    }
    // wave-uniform destination select
    unsigned short* dst; int jloc;
    if (jbase < CD)            { dst = Qb;  jloc = jbase; }
    else if (jbase < 2 * CD)   { dst = Kb;  jloc = jbase - CD; }
    else                       { dst = Vtb; jloc = jbase - 2 * CD; }
    const int h = jloc >> 6;
    #pragma unroll
    for (int mf = 0; mf < 4; ++mf) {
        #pragma unroll
        for (int nf = 0; nf < 4; ++nf) {
            const int d = (jloc & 63) + nf * 16 + colw;   // jloc&63==0; d = nf*16+colw
            #pragma unroll
            for (int r = 0; r < 4; ++r) {
                const int i  = i0 + wm * 64 + mf * 16 + grp * 4 + r;
                const int bt = i >> 9, li = i & 511;
                const unsigned short hv = f2bf(acc[mf][nf][r] * inv[mf][r]);
                if (jbase < 2 * CD)
                    dst[(((size_t)(bt * HEADS + h)) * LSEQ + li) * DH + d] = hv;     // Q or K [l][d]
                else
                    dst[(((size_t)(bt * HEADS + h)) * DH + d) * LSEQ + li] = hv;     // V transposed [d][l]
            }
        }
    }
}

// ---------------- Kernel 2: flash attention per (b,t,h) ----------
__global__ __launch_bounds__(256)
void attn_kernel(const unsigned short* __restrict__ Qb,
                 const unsigned short* __restrict__ Kb,
                 const unsigned short* __restrict__ Vtb,
                 unsigned short* __restrict__ Ob)
{
    __shared__ __attribute__((aligned(16))) unsigned short Psm[4][16 * 40];

    const int tid  = threadIdx.x;
    const int wv   = tid >> 6;
    const int lane = tid & 63;
    const int colw = lane & 15;
    const int grp  = lane >> 4;

    const int bth = blockIdx.x >> 3;      // 0..255
    const int qt  = blockIdx.x & 7;
    const int q0  = qt * 64 + wv * 16;    // wave's first q row

    const unsigned short* Qh = Qb  + (size_t)bth * LSEQ * DH;
    const unsigned short* Kh = Kb  + (size_t)bth * LSEQ * DH;
    const unsigned short* Vh = Vtb + (size_t)bth * DH * LSEQ;

    short8 aq[2];
    #pragma unroll
    for (int ks = 0; ks < 2; ++ks)
        aq[ks] = *(const short8*)&Qh[(size_t)(q0 + colw) * DH + ks * 32 + grp * 8];

    float m[4], lsum[4];
    f32x4 oacc[4] = {};
    #pragma unroll
    for (int r = 0; r < 4; ++r) { m[r] = -INFINITY; lsum[r] = 0.f; }

    for (int kv0 = 0; kv0 < LSEQ; kv0 += 32) {
        f32x4 s0 = {}, s1 = {};
        #pragma unroll
        for (int ks = 0; ks < 2; ++ks) {
            const short8 b0 = *(const short8*)&Kh[(size_t)(kv0 + colw) * DH + ks * 32 + grp * 8];
            const short8 b1 = *(const short8*)&Kh[(size_t)(kv0 + 16 + colw) * DH + ks * 32 + grp * 8];
            s0 = __builtin_amdgcn_mfma_f32_16x16x32_bf16(aq[ks], b0, s0, 0, 0, 0);
            s1 = __builtin_amdgcn_mfma_f32_16x16x32_bf16(aq[ks], b1, s1, 0, 0, 0);
        }
        float mn[4], corr[4];
        #pragma unroll
        for (int r = 0; r < 4; ++r) {
            float t = fmaxf(s0[r], s1[r]);
            t = fmaxf(t, __shfl_xor(t, 1));
            t = fmaxf(t, __shfl_xor(t, 2));
            t = fmaxf(t, __shfl_xor(t, 4));
            t = fmaxf(t, __shfl_xor(t, 8));
            mn[r]   = fmaxf(m[r], t);
            corr[r] = __expf(m[r] - mn[r]);
            m[r]    = mn[r];
        }
        float p0[4], p1[4];
        #pragma unroll
        for (int r = 0; r < 4; ++r) {
            p0[r] = __expf(s0[r] - mn[r]);
            p1[r] = __expf(s1[r] - mn[r]);
            float t = p0[r] + p1[r];
            t += __shfl_xor(t, 1);
            t += __shfl_xor(t, 2);
            t += __shfl_xor(t, 4);
            t += __shfl_xor(t, 8);
            lsum[r] = lsum[r] * corr[r] + t;
        }
        #pragma unroll
        for (int nd = 0; nd < 4; ++nd)
            #pragma unroll
            for (int r = 0; r < 4; ++r) oacc[nd][r] *= corr[r];

        // P (C-layout) -> LDS -> A-layout fragments
        #pragma unroll
        for (int r = 0; r < 4; ++r) {
            Psm[wv][(grp * 4 + r) * 40 + colw]      = f2bf(p0[r]);
            Psm[wv][(grp * 4 + r) * 40 + 16 + colw] = f2bf(p1[r]);
        }
        const short8 ap = *(const short8*)&Psm[wv][colw * 40 + grp * 8];
        #pragma unroll
        for (int nd = 0; nd < 4; ++nd) {
            const short8 bvv = *(const short8*)&Vh[(size_t)(nd * 16 + colw) * LSEQ + kv0 + grp * 8];
            oacc[nd] = __builtin_amdgcn_mfma_f32_16x16x32_bf16(ap, bvv, oacc[nd], 0, 0, 0);
        }
    }

    const int bt = bth >> 4, h = bth & 15;
    #pragma unroll
    for (int nd = 0; nd < 4; ++nd) {
        #pragma unroll
        for (int r = 0; r < 4; ++r) {
            const int i = bt * LSEQ + q0 + grp * 4 + r;
            const int c = h * 64 + nd * 16 + colw;
            Ob[(size_t)i * CD + c] = f2bf(oacc[nd][r] / lsum[r]);
        }
    }
}

// ---------------- Kernel 3: output projection + bias + residual ----------
__global__ __launch_bounds__(512, 2)
void proj_out_kernel(const unsigned short* __restrict__ Ob,
                     const unsigned short* __restrict__ wmb,
                     const float* __restrict__ bm,
                     const float* __restrict__ x, float* __restrict__ out)
{
    __shared__ __attribute__((aligned(16))) char lds[96 * 1024];

    // grid = 256 (64 m-tiles x 4 n-tiles), bijective XCD swizzle
    const int wg   = (blockIdx.x & 7) * 32 + (blockIdx.x >> 3);
    const int in_t = wg >> 6, im_t = wg & 63;
    const int i0 = im_t * 128, n0 = in_t * 256;

    const int tid  = threadIdx.x;
    const int w    = tid >> 6;
    const int lane = tid & 63;
    const int colw = lane & 15;
    const int grp  = lane >> 4;
    const int wm   = w >> 2, wn = w & 3;

    f32x4 acc[4][4] = {};
    gemm_core(Ob, wmb, i0, n0, lds, acc);

    #pragma unroll
    for (int nf = 0; nf < 4; ++nf) {
        const int j = n0 + wn * 64 + nf * 16 + colw;
        const float bv = bm[j];
        #pragma unroll
        for (int mf = 0; mf < 4; ++mf) {
            #pragma unroll
            for (int r = 0; r < 4; ++r) {
                const int i = i0 + wm * 64 + mf * 16 + grp * 4 + r;
                out[(size_t)i * CD + j] = acc[mf][nf][r] + bv + x[(size_t)i * CD + j];
            }
        }
    }
}

extern "C" void kernel_launch(void* const* d_in, const int* in_sizes, int n_in,
                              void* d_out, int out_size, void* d_ws, size_t ws_size,
                              hipStream_t stream) {
    const float* x   = (const float*)d_in[0];
    const float* wq  = (const float*)d_in[1];
    const float* bq  = (const float*)d_in[2];
    const float* wkv = (const float*)d_in[3];
    const float* bkv = (const float*)d_in[4];
    const float* wm  = (const float*)d_in[5];
    const float* bm  = (const float*)d_in[6];
    float* out = (float*)d_out;

    // ws layout (64 MB, timeline-aliased):
    //  R0: xb (convert->proj_qkv), then Ob (attn->proj_out)
    //  R1: Qb (proj_qkv->attn), then wmb (cvt-after-attn->proj_out)
    //  R2: Kb   R3: Vtb
    // wqkvb lives in d_out (dead before proj_out writes it).
    const size_t SEG = (size_t)MROWS * CD;
    unsigned short* xb    = (unsigned short*)d_ws;
    unsigned short* Ob    = xb;
    unsigned short* Qb    = xb + SEG;
    unsigned short* wmb   = Qb;
    unsigned short* Kb    = Qb + SEG;
    unsigned short* Vtb   = Kb + SEG;
    unsigned short* wqkvb = (unsigned short*)d_out;

    cvt_kernel<<<2048, 256, 0, stream>>>(x,   xb,    (MROWS * CD) / 4);
    cvt_kernel<<<1024, 256, 0, stream>>>(wq,  wqkvb, (CD * CD) / 4);
    cvt_kernel<<<1024, 256, 0, stream>>>(wkv, wqkvb + (size_t)CD * CD, (2 * CD * CD) / 4);
    proj_qkv_kernel<<<768, 512, 0, stream>>>(xb, wqkvb, bq, bkv, Qb, Kb, Vtb);
    attn_kernel<<<2048, 256, 0, stream>>>(Qb, Kb, Vtb, Ob);
    cvt_kernel<<<1024, 256, 0, stream>>>(wm, wmb, (CD * CD) / 4);
    proj_out_kernel<<<256, 512, 0, stream>>>(Ob, wmb, bm, x, out);
}

// Round 4
// 268.023 us; speedup vs baseline: 1.2469x; 1.0049x over previous
//
#include <hip/hip_runtime.h>
#include <hip/hip_bf16.h>

typedef __attribute__((ext_vector_type(8))) short short8;
typedef __attribute__((ext_vector_type(4))) float f32x4;

#define HEADS 16
#define DH    64
#define LSEQ  512
#define CD    1024
#define MROWS 8192            /* B*T*L */

static __device__ __forceinline__ unsigned short f2bf(float f) {
    union { float f; unsigned int u; } v; v.f = f;
    unsigned int u = v.u;
    u += 0x7fffu + ((u >> 16) & 1u);   // round-to-nearest-even
    return (unsigned short)(u >> 16);
}

static __device__ __forceinline__ void gload16(const unsigned short* g, char* lds) {
    __builtin_amdgcn_global_load_lds(
        (const __attribute__((address_space(1))) void*)g,
        (__attribute__((address_space(3))) void*)lds, 16, 0, 0);
}

// ---------------- f32 -> bf16 bulk convert (vec4) ----------------
__global__ __launch_bounds__(256)
void cvt_kernel(const float* __restrict__ s, unsigned short* __restrict__ d, int n4) {
    union U { unsigned short us[4]; unsigned long long u; };
    for (int i = blockIdx.x * blockDim.x + threadIdx.x; i < n4; i += gridDim.x * blockDim.x) {
        const float4 v = ((const float4*)s)[i];
        U p; p.us[0] = f2bf(v.x); p.us[1] = f2bf(v.y); p.us[2] = f2bf(v.z); p.us[3] = f2bf(v.w);
        ((unsigned long long*)d)[i] = p.u;
    }
}

// ================= multi-phase GEMM core (T3+T4+T2+T5) =================
// BM=128, BN=256, BK=32, 8 waves (2M x 4N), ring-4 LDS (24 KB/slot = 96 KB).
#define SLOT_BYTES (24 * 1024)

static __device__ __forceinline__ void gemm_core(
    const unsigned short* __restrict__ Ap,   // [M][CD] bf16
    const unsigned short* __restrict__ Bp,   // [N][CD] bf16
    int i0, int n0, char* lds, f32x4 acc[4][4])
{
    const int tid  = threadIdx.x;
    const int w    = tid >> 6;        // 0..7
    const int lane = tid & 63;
    const int colw = lane & 15;
    const int grp  = lane >> 4;
    const int wm   = w >> 2;          // 0..1
    const int wn   = w & 3;           // 0..3

    // ---- staging constants (per-lane pre-swizzled global source) ----
    const int cl   = (lane & 7) ^ (lane >> 3);   // logical chunk (phys chunk = lane&7)
    const int bsel = cl >> 2;                    // tile-row parity within LDS row
    const int kc   = (cl & 3) * 8;               // element offset within 32-col K slice
    const int arow = 2 * (w * 8  + (lane >> 3)) + bsel;   // 0..127
    const int brow = 2 * (w * 16 + (lane >> 3)) + bsel;   // s=0 row; s=1 adds 16
    const unsigned short* Ag  = Ap + (size_t)(i0 + arow) * CD + kc;
    const unsigned short* Bg0 = Bp + (size_t)(n0 + brow) * CD + kc;
    const unsigned short* Bg1 = Bp + (size_t)(n0 + brow + 16) * CD + kc;
    char* const adst  = lds + w * 8 * 128;
    char* const bdst0 = lds + 8192 + w * 16 * 128;
    char* const bdst1 = bdst0 + 8 * 128;

    // ---- fragment ds_read byte offsets (swizzled) ----
    int aoff[4], boff[4];
    #pragma unroll
    for (int mf = 0; mf < 4; ++mf) {
        const int rr = wm * 64 + mf * 16 + colw;
        aoff[mf] = (rr >> 1) * 128 + (((((rr & 1) << 2) | grp) ^ ((rr >> 1) & 7)) << 4);
    }
    #pragma unroll
    for (int nf = 0; nf < 4; ++nf) {
        const int rr = wn * 64 + nf * 16 + colw;
        boff[nf] = 8192 + (rr >> 1) * 128 + (((((rr & 1) << 2) | grp) ^ ((rr >> 1) & 7)) << 4);
    }

    const int NT = CD / 32;   // 32 K-tiles

    // ---- prologue: stage tiles 0,1,2 ----
    #pragma unroll
    for (int t = 0; t < 3; ++t) {
        char* sb = lds + t * SLOT_BYTES;
        gload16(Ag  + t * 32, sb + (adst  - lds));
        gload16(Bg0 + t * 32, sb + (bdst0 - lds));
        gload16(Bg1 + t * 32, sb + (bdst1 - lds));
    }
    asm volatile("s_waitcnt vmcnt(6)" ::: "memory");
    __builtin_amdgcn_sched_barrier(0);
    __builtin_amdgcn_s_barrier();

    #pragma unroll 4
    for (int t = 0; t < NT; ++t) {
        const char* sb = lds + (t & 3) * SLOT_BYTES;
        short8 af[4], bf[4];
        #pragma unroll
        for (int mf = 0; mf < 4; ++mf) af[mf] = *(const short8*)(sb + aoff[mf]);
        #pragma unroll
        for (int nf = 0; nf < 4; ++nf) bf[nf] = *(const short8*)(sb + boff[nf]);

        // stage tile t+3 (clamped tail: redundant re-stage into a dead slot)
        const int tn = (t + 3 < NT) ? t + 3 : NT - 1;
        char* db = lds + ((t + 3) & 3) * SLOT_BYTES;
        gload16(Ag  + tn * 32, db + (adst  - lds));
        gload16(Bg0 + tn * 32, db + (bdst0 - lds));
        gload16(Bg1 + tn * 32, db + (bdst1 - lds));

        __builtin_amdgcn_s_setprio(1);
        #pragma unroll
        for (int nf = 0; nf < 4; ++nf)
            #pragma unroll
            for (int mf = 0; mf < 4; ++mf)
                acc[mf][nf] = __builtin_amdgcn_mfma_f32_16x16x32_bf16(af[mf], bf[nf], acc[mf][nf], 0, 0, 0);
        __builtin_amdgcn_s_setprio(0);

        asm volatile("s_waitcnt vmcnt(6)" ::: "memory");   // gate: tile t+1 fully staged
        __builtin_amdgcn_sched_barrier(0);
        __builtin_amdgcn_s_barrier();
    }
}

// ---------------- Kernel 1: fused QKV projection ----------
__global__ __launch_bounds__(512, 2)
void proj_qkv_kernel(const unsigned short* __restrict__ xb,
                     const unsigned short* __restrict__ wqkvb,
                     const float* __restrict__ bq, const float* __restrict__ bkv,
                     unsigned short* __restrict__ Qb, unsigned short* __restrict__ Kb,
                     unsigned short* __restrict__ Vtb)
{
    __shared__ __attribute__((aligned(16))) char lds[96 * 1024];

    // grid = 768 (64 m-tiles x 12 n-tiles), bijective XCD swizzle (nwg%8==0)
    const int wg   = (blockIdx.x & 7) * 96 + (blockIdx.x >> 3);
    const int in_t = wg / 64, im_t = wg % 64;
    const int i0 = im_t * 128, n0 = in_t * 256;

    const int tid  = threadIdx.x;
    const int w    = tid >> 6;
    const int lane = tid & 63;
    const int colw = lane & 15;
    const int grp  = lane >> 4;
    const int wm   = w >> 2, wn = w & 3;

    f32x4 acc[4][4] = {};
    gemm_core(xb, wqkvb, i0, n0, lds, acc);

    // ---- epilogue: bias + l2norm over 64-col head; scatter store ----
    const int jbase = n0 + wn * 64;               // head-aligned, wave-uniform
    const float* bp = (jbase < CD) ? (bq + jbase) : (bkv + (jbase - CD));
    #pragma unroll
    for (int nf = 0; nf < 4; ++nf) {
        const float bv = bp[nf * 16 + colw];
        #pragma unroll
        for (int mf = 0; mf < 4; ++mf)
            #pragma unroll
            for (int r = 0; r < 4; ++r) acc[mf][nf][r] += bv;
    }
    const float qscale = (jbase < CD) ? 0.125f : 1.0f;
    float inv[4][4];
    #pragma unroll
    for (int mf = 0; mf < 4; ++mf) {
        #pragma unroll
        for (int r = 0; r < 4; ++r) {
            float t = 0.f;
            #pragma unroll
            for (int nf = 0; nf < 4; ++nf) t += acc[mf][nf][r] * acc[mf][nf][r];
            t += __shfl_xor(t, 1);
            t += __shfl_xor(t, 2);
            t += __shfl_xor(t, 4);
            t += __shfl_xor(t, 8);
            inv[mf][r] = qscale / fmaxf(sqrtf(t), 1e-12f);
        }
    }
    // wave-uniform destination select
    unsigned short* dst; int jloc;
    if (jbase < CD)            { dst = Qb;  jloc = jbase; }
    else if (jbase < 2 * CD)   { dst = Kb;  jloc = jbase - CD; }
    else                       { dst = Vtb; jloc = jbase - 2 * CD; }
    const int h = jloc >> 6;
    #pragma unroll
    for (int mf = 0; mf < 4; ++mf) {
        #pragma unroll
        for (int nf = 0; nf < 4; ++nf) {
            const int d = nf * 16 + colw;
            #pragma unroll
            for (int r = 0; r < 4; ++r) {
                const int i  = i0 + wm * 64 + mf * 16 + grp * 4 + r;
                const int bt = i >> 9, li = i & 511;
                const unsigned short hv = f2bf(acc[mf][nf][r] * inv[mf][r]);
                if (jbase < 2 * CD)
                    dst[(((size_t)(bt * HEADS + h)) * LSEQ + li) * DH + d] = hv;     // Q or K [l][d]
                else
                    dst[(((size_t)(bt * HEADS + h)) * DH + d) * LSEQ + li] = hv;     // V transposed [d][l]
            }
        }
    }
}

// ---------------- Kernel 2: flash attention per (b,t,h) ----------
// Bounded-score softmax: |s| <= 0.125 (l2norm'd q,k; 1/sqrt(D) folded into q),
// so exp(s) directly — no max tracking, no rescales, per-lane running sum.
// blockIdx mapping: bth = blockIdx&255 so all 8 q-tiles of a head share an XCD.
__global__ __launch_bounds__(256)
void attn_kernel(const unsigned short* __restrict__ Qb,
                 const unsigned short* __restrict__ Kb,
                 const unsigned short* __restrict__ Vtb,
                 unsigned short* __restrict__ Ob)
{
    __shared__ __attribute__((aligned(16))) unsigned short Psm[4][16 * 40];

    const int tid  = threadIdx.x;
    const int wv   = tid >> 6;
    const int lane = tid & 63;
    const int colw = lane & 15;
    const int grp  = lane >> 4;

    const int bth = blockIdx.x & 255;     // head id (same XCD for all its q-tiles)
    const int qt  = blockIdx.x >> 8;      // 0..7
    const int q0  = qt * 64 + wv * 16;    // wave's first q row

    const unsigned short* Qh = Qb  + (size_t)bth * LSEQ * DH;
    const unsigned short* Kh = Kb  + (size_t)bth * LSEQ * DH;
    const unsigned short* Vh = Vtb + (size_t)bth * DH * LSEQ;

    short8 aq[2];
    #pragma unroll
    for (int ks = 0; ks < 2; ++ks)
        aq[ks] = *(const short8*)&Qh[(size_t)(q0 + colw) * DH + ks * 32 + grp * 8];

    float plsum[4] = {0.f, 0.f, 0.f, 0.f};
    f32x4 oacc[4] = {};

    for (int kv0 = 0; kv0 < LSEQ; kv0 += 32) {
        f32x4 s0 = {}, s1 = {};
        #pragma unroll
        for (int ks = 0; ks < 2; ++ks) {
            const short8 b0 = *(const short8*)&Kh[(size_t)(kv0 + colw) * DH + ks * 32 + grp * 8];
            const short8 b1 = *(const short8*)&Kh[(size_t)(kv0 + 16 + colw) * DH + ks * 32 + grp * 8];
            s0 = __builtin_amdgcn_mfma_f32_16x16x32_bf16(aq[ks], b0, s0, 0, 0, 0);
            s1 = __builtin_amdgcn_mfma_f32_16x16x32_bf16(aq[ks], b1, s1, 0, 0, 0);
        }
        // p = exp(s); |s|<=0.125 so no max subtraction needed; softmax is
        // shift-invariant so this matches the reference exactly.
        float p0[4], p1[4];
        #pragma unroll
        for (int r = 0; r < 4; ++r) {
            p0[r] = __expf(s0[r]);
            p1[r] = __expf(s1[r]);
            plsum[r] += p0[r] + p1[r];
        }
        // P (C-layout) -> LDS -> A-layout fragments
        #pragma unroll
        for (int r = 0; r < 4; ++r) {
            Psm[wv][(grp * 4 + r) * 40 + colw]      = f2bf(p0[r]);
            Psm[wv][(grp * 4 + r) * 40 + 16 + colw] = f2bf(p1[r]);
        }
        const short8 ap = *(const short8*)&Psm[wv][colw * 40 + grp * 8];
        #pragma unroll
        for (int nd = 0; nd < 4; ++nd) {
            const short8 bvv = *(const short8*)&Vh[(size_t)(nd * 16 + colw) * LSEQ + kv0 + grp * 8];
            oacc[nd] = __builtin_amdgcn_mfma_f32_16x16x32_bf16(ap, bvv, oacc[nd], 0, 0, 0);
        }
    }

    // single cross-lane reduce of the row sums (16-lane groups)
    float oinv[4];
    #pragma unroll
    for (int r = 0; r < 4; ++r) {
        float t = plsum[r];
        t += __shfl_xor(t, 1);
        t += __shfl_xor(t, 2);
        t += __shfl_xor(t, 4);
        t += __shfl_xor(t, 8);
        oinv[r] = 1.0f / t;
    }

    const int bt = bth >> 4, h = bth & 15;
    #pragma unroll
    for (int nd = 0; nd < 4; ++nd) {
        #pragma unroll
        for (int r = 0; r < 4; ++r) {
            const int i = bt * LSEQ + q0 + grp * 4 + r;
            const int c = h * 64 + nd * 16 + colw;
            Ob[(size_t)i * CD + c] = f2bf(oacc[nd][r] * oinv[r]);
        }
    }
}

// ---------------- Kernel 3: output projection + bias + residual ----------
__global__ __launch_bounds__(512, 2)
void proj_out_kernel(const unsigned short* __restrict__ Ob,
                     const unsigned short* __restrict__ wmb,
                     const float* __restrict__ bm,
                     const float* __restrict__ x, float* __restrict__ out)
{
    __shared__ __attribute__((aligned(16))) char lds[96 * 1024];

    // grid = 256 (64 m-tiles x 4 n-tiles), bijective XCD swizzle
    const int wg   = (blockIdx.x & 7) * 32 + (blockIdx.x >> 3);
    const int in_t = wg >> 6, im_t = wg & 63;
    const int i0 = im_t * 128, n0 = in_t * 256;

    const int tid  = threadIdx.x;
    const int w    = tid >> 6;
    const int lane = tid & 63;
    const int colw = lane & 15;
    const int grp  = lane >> 4;
    const int wm   = w >> 2, wn = w & 3;

    f32x4 acc[4][4] = {};
    gemm_core(Ob, wmb, i0, n0, lds, acc);

    #pragma unroll
    for (int nf = 0; nf < 4; ++nf) {
        const int j = n0 + wn * 64 + nf * 16 + colw;
        const float bv = bm[j];
        #pragma unroll
        for (int mf = 0; mf < 4; ++mf) {
            #pragma unroll
            for (int r = 0; r < 4; ++r) {
                const int i = i0 + wm * 64 + mf * 16 + grp * 4 + r;
                out[(size_t)i * CD + j] = acc[mf][nf][r] + bv + x[(size_t)i * CD + j];
            }
        }
    }
}

extern "C" void kernel_launch(void* const* d_in, const int* in_sizes, int n_in,
                              void* d_out, int out_size, void* d_ws, size_t ws_size,
                              hipStream_t stream) {
    const float* x   = (const float*)d_in[0];
    const float* wq  = (const float*)d_in[1];
    const float* bq  = (const float*)d_in[2];
    const float* wkv = (const float*)d_in[3];
    const float* bkv = (const float*)d_in[4];
    const float* wm  = (const float*)d_in[5];
    const float* bm  = (const float*)d_in[6];
    float* out = (float*)d_out;

    // ws layout (64 MB, timeline-aliased):
    //  R0: xb (convert->proj_qkv), then Ob (attn->proj_out)
    //  R1: Qb (proj_qkv->attn), then wmb (cvt-after-attn->proj_out)
    //  R2: Kb   R3: Vtb
    // wqkvb lives in d_out (dead before proj_out writes it).
    const size_t SEG = (size_t)MROWS * CD;
    unsigned short* xb    = (unsigned short*)d_ws;
    unsigned short* Ob    = xb;
    unsigned short* Qb    = xb + SEG;
    unsigned short* wmb   = Qb;
    unsigned short* Kb    = Qb + SEG;
    unsigned short* Vtb   = Kb + SEG;
    unsigned short* wqkvb = (unsigned short*)d_out;

    cvt_kernel<<<2048, 256, 0, stream>>>(x,   xb,    (MROWS * CD) / 4);
    cvt_kernel<<<1024, 256, 0, stream>>>(wq,  wqkvb, (CD * CD) / 4);
    cvt_kernel<<<1024, 256, 0, stream>>>(wkv, wqkvb + (size_t)CD * CD, (2 * CD * CD) / 4);
    proj_qkv_kernel<<<768, 512, 0, stream>>>(xb, wqkvb, bq, bkv, Qb, Kb, Vtb);
    attn_kernel<<<2048, 256, 0, stream>>>(Qb, Kb, Vtb, Ob);
    cvt_kernel<<<1024, 256, 0, stream>>>(wm, wmb, (CD * CD) / 4);
    proj_out_kernel<<<256, 512, 0, stream>>>(Ob, wmb, bm, x, out);
}

// Round 5
// 185.670 us; speedup vs baseline: 1.7999x; 1.4435x over previous
//
#include <hip/hip_runtime.h>
#include <hip/hip_bf16.h>

typedef __attribute__((ext_vector_type(8))) short short8;
typedef __attribute__((ext_vector_type(4))) float f32x4;

#define HEADS 16
#define DH    64
#define LSEQ  512
#define CD    1024
#define MROWS 8192            /* B*T*L */

static __device__ __forceinline__ unsigned short f2bf(float f) {
    union { float f; unsigned int u; } v; v.f = f;
    unsigned int u = v.u;
    u += 0x7fffu + ((u >> 16) & 1u);   // round-to-nearest-even
    return (unsigned short)(u >> 16);
}

static __device__ __forceinline__ void gload16(const unsigned short* g, char* lds) {
    __builtin_amdgcn_global_load_lds(
        (const __attribute__((address_space(1))) void*)g,
        (__attribute__((address_space(3))) void*)lds, 16, 0, 0);
}

// ---------------- f32 -> bf16 bulk convert (vec4) ----------------
__global__ __launch_bounds__(256)
void cvt_kernel(const float* __restrict__ s, unsigned short* __restrict__ d, int n4) {
    union U { unsigned short us[4]; unsigned long long u; };
    for (int i = blockIdx.x * blockDim.x + threadIdx.x; i < n4; i += gridDim.x * blockDim.x) {
        const float4 v = ((const float4*)s)[i];
        U p; p.us[0] = f2bf(v.x); p.us[1] = f2bf(v.y); p.us[2] = f2bf(v.z); p.us[3] = f2bf(v.w);
        ((unsigned long long*)d)[i] = p.u;
    }
}

// ================= multi-phase GEMM core (T3+T4+T2+T5) =================
// BM=128, BN=256, BK=32, 8 waves (2M x 4N), ring-4 LDS (24 KB/slot = 96 KB).
#define SLOT_BYTES (24 * 1024)

static __device__ __forceinline__ void gemm_core(
    const unsigned short* __restrict__ Ap,   // [M][CD] bf16
    const unsigned short* __restrict__ Bp,   // [N][CD] bf16
    int i0, int n0, char* lds, f32x4 acc[4][4])
{
    const int tid  = threadIdx.x;
    const int w    = tid >> 6;        // 0..7
    const int lane = tid & 63;
    const int colw = lane & 15;
    const int grp  = lane >> 4;
    const int wm   = w >> 2;          // 0..1
    const int wn   = w & 3;           // 0..3

    // ---- staging constants (per-lane pre-swizzled global source) ----
    const int cl   = (lane & 7) ^ (lane >> 3);   // logical chunk (phys chunk = lane&7)
    const int bsel = cl >> 2;                    // tile-row parity within LDS row
    const int kc   = (cl & 3) * 8;               // element offset within 32-col K slice
    const int arow = 2 * (w * 8  + (lane >> 3)) + bsel;   // 0..127
    const int brow = 2 * (w * 16 + (lane >> 3)) + bsel;   // s=0 row; s=1 adds 16
    const unsigned short* Ag  = Ap + (size_t)(i0 + arow) * CD + kc;
    const unsigned short* Bg0 = Bp + (size_t)(n0 + brow) * CD + kc;
    const unsigned short* Bg1 = Bp + (size_t)(n0 + brow + 16) * CD + kc;
    char* const adst  = lds + w * 8 * 128;
    char* const bdst0 = lds + 8192 + w * 16 * 128;
    char* const bdst1 = bdst0 + 8 * 128;

    // ---- fragment ds_read byte offsets (swizzled) ----
    int aoff[4], boff[4];
    #pragma unroll
    for (int mf = 0; mf < 4; ++mf) {
        const int rr = wm * 64 + mf * 16 + colw;
        aoff[mf] = (rr >> 1) * 128 + (((((rr & 1) << 2) | grp) ^ ((rr >> 1) & 7)) << 4);
    }
    #pragma unroll
    for (int nf = 0; nf < 4; ++nf) {
        const int rr = wn * 64 + nf * 16 + colw;
        boff[nf] = 8192 + (rr >> 1) * 128 + (((((rr & 1) << 2) | grp) ^ ((rr >> 1) & 7)) << 4);
    }

    const int NT = CD / 32;   // 32 K-tiles

    // ---- prologue: stage tiles 0,1,2 ----
    #pragma unroll
    for (int t = 0; t < 3; ++t) {
        char* sb = lds + t * SLOT_BYTES;
        gload16(Ag  + t * 32, sb + (adst  - lds));
        gload16(Bg0 + t * 32, sb + (bdst0 - lds));
        gload16(Bg1 + t * 32, sb + (bdst1 - lds));
    }
    asm volatile("s_waitcnt vmcnt(6)" ::: "memory");
    __builtin_amdgcn_sched_barrier(0);
    __builtin_amdgcn_s_barrier();

    #pragma unroll 4
    for (int t = 0; t < NT; ++t) {
        const char* sb = lds + (t & 3) * SLOT_BYTES;
        short8 af[4], bf[4];
        #pragma unroll
        for (int mf = 0; mf < 4; ++mf) af[mf] = *(const short8*)(sb + aoff[mf]);
        #pragma unroll
        for (int nf = 0; nf < 4; ++nf) bf[nf] = *(const short8*)(sb + boff[nf]);

        // stage tile t+3 (clamped tail: redundant re-stage into a dead slot)
        const int tn = (t + 3 < NT) ? t + 3 : NT - 1;
        char* db = lds + ((t + 3) & 3) * SLOT_BYTES;
        gload16(Ag  + tn * 32, db + (adst  - lds));
        gload16(Bg0 + tn * 32, db + (bdst0 - lds));
        gload16(Bg1 + tn * 32, db + (bdst1 - lds));

        __builtin_amdgcn_s_setprio(1);
        #pragma unroll
        for (int nf = 0; nf < 4; ++nf)
            #pragma unroll
            for (int mf = 0; mf < 4; ++mf)
                acc[mf][nf] = __builtin_amdgcn_mfma_f32_16x16x32_bf16(af[mf], bf[nf], acc[mf][nf], 0, 0, 0);
        __builtin_amdgcn_s_setprio(0);

        asm volatile("s_waitcnt vmcnt(6)" ::: "memory");   // gate: tile t+1 fully staged
        __builtin_amdgcn_sched_barrier(0);
        __builtin_amdgcn_s_barrier();
    }
}

// ---------------- Kernel 1: fused QKV projection ----------
__global__ __launch_bounds__(512, 2)
void proj_qkv_kernel(const unsigned short* __restrict__ xb,
                     const unsigned short* __restrict__ wqkvb,
                     const float* __restrict__ bq, const float* __restrict__ bkv,
                     unsigned short* __restrict__ Qb, unsigned short* __restrict__ Kb,
                     unsigned short* __restrict__ Vtb)
{
    __shared__ __attribute__((aligned(16))) char lds[96 * 1024];

    // grid = 768 (64 m-tiles x 12 n-tiles), bijective XCD swizzle (nwg%8==0)
    const int wg   = (blockIdx.x & 7) * 96 + (blockIdx.x >> 3);
    const int in_t = wg / 64, im_t = wg % 64;
    const int i0 = im_t * 128, n0 = in_t * 256;

    const int tid  = threadIdx.x;
    const int w    = tid >> 6;
    const int lane = tid & 63;
    const int colw = lane & 15;
    const int grp  = lane >> 4;
    const int wm   = w >> 2, wn = w & 3;

    f32x4 acc[4][4] = {};
    gemm_core(xb, wqkvb, i0, n0, lds, acc);

    // ---- epilogue: bias + l2norm over 64-col head; scatter store ----
    const int jbase = n0 + wn * 64;               // head-aligned, wave-uniform
    const float* bp = (jbase < CD) ? (bq + jbase) : (bkv + (jbase - CD));
    #pragma unroll
    for (int nf = 0; nf < 4; ++nf) {
        const float bv = bp[nf * 16 + colw];
        #pragma unroll
        for (int mf = 0; mf < 4; ++mf)
            #pragma unroll
            for (int r = 0; r < 4; ++r) acc[mf][nf][r] += bv;
    }
    const float qscale = (jbase < CD) ? 0.125f : 1.0f;
    float inv[4][4];
    #pragma unroll
    for (int mf = 0; mf < 4; ++mf) {
        #pragma unroll
        for (int r = 0; r < 4; ++r) {
            float t = 0.f;
            #pragma unroll
            for (int nf = 0; nf < 4; ++nf) t += acc[mf][nf][r] * acc[mf][nf][r];
            t += __shfl_xor(t, 1);
            t += __shfl_xor(t, 2);
            t += __shfl_xor(t, 4);
            t += __shfl_xor(t, 8);
            inv[mf][r] = qscale / fmaxf(sqrtf(t), 1e-12f);
        }
    }
    // wave-uniform destination select
    unsigned short* dst; int jloc;
    if (jbase < CD)            { dst = Qb;  jloc = jbase; }
    else if (jbase < 2 * CD)   { dst = Kb;  jloc = jbase - CD; }
    else                       { dst = Vtb; jloc = jbase - 2 * CD; }
    const int h = jloc >> 6;
    #pragma unroll
    for (int mf = 0; mf < 4; ++mf) {
        #pragma unroll
        for (int nf = 0; nf < 4; ++nf) {
            const int d = nf * 16 + colw;
            #pragma unroll
            for (int r = 0; r < 4; ++r) {
                const int i  = i0 + wm * 64 + mf * 16 + grp * 4 + r;
                const int bt = i >> 9, li = i & 511;
                const unsigned short hv = f2bf(acc[mf][nf][r] * inv[mf][r]);
                if (jbase < 2 * CD)
                    dst[(((size_t)(bt * HEADS + h)) * LSEQ + li) * DH + d] = hv;     // Q or K [l][d]
                else
                    // V tiled: [bth][l/64][d][64] -> contiguous 8KB kv-tiles for attn
                    dst[((((size_t)(bt * HEADS + h)) * 8 + (li >> 6)) * DH + d) * 64 + (li & 63)] = hv;
            }
        }
    }
}

// ---------------- Kernel 2: flash attention per (b,t,h) ----------
// Bounded-score softmax (|s|<=0.125): exp(s) directly, no max tracking.
// 8 waves x 16 q-rows = 128 q/block; K/V kv-tiles (64x64, contiguous 8KB)
// staged in LDS once per block via global_load_lds, XOR-swizzled both sides.
__global__ __launch_bounds__(512)
void attn_kernel(const unsigned short* __restrict__ Qb,
                 const unsigned short* __restrict__ Kb,
                 const unsigned short* __restrict__ Vtb,   // tiled [bth][8][64][64]
                 unsigned short* __restrict__ Ob)
{
    __shared__ __attribute__((aligned(16))) unsigned short Ksm[64 * 64];
    __shared__ __attribute__((aligned(16))) unsigned short Vsm[64 * 64];
    __shared__ __attribute__((aligned(16))) unsigned short Psm[8][16 * 72];

    const int tid  = threadIdx.x;
    const int w    = tid >> 6;        // 0..7
    const int lane = tid & 63;
    const int colw = lane & 15;
    const int grp  = lane >> 4;

    const int bth = blockIdx.x & 255;     // head id (same XCD for all its q-tiles)
    const int qt  = blockIdx.x >> 8;      // 0..3
    const int q0  = qt * 128 + w * 16;    // wave's first q row

    const unsigned short* Qh = Qb  + (size_t)bth * LSEQ * DH;
    const unsigned short* Kh = Kb  + (size_t)bth * LSEQ * DH;
    const unsigned short* Vh = Vtb + (size_t)bth * LSEQ * DH;  // tiled

    short8 aq[2];
    #pragma unroll
    for (int ks = 0; ks < 2; ++ks)
        aq[ks] = *(const short8*)&Qh[(size_t)(q0 + colw) * DH + ks * 32 + grp * 8];

    // staging source (pre-swizzled): LDS linear dest = wave base + lane*16
    const int srow   = w * 8 + (lane >> 3);          // 0..63
    const int schunk = (lane & 7) ^ (srow & 7);      // swizzled 16B chunk
    const int goff   = srow * DH + schunk * 8;       // element offset in 8KB tile
    char* const kdst = (char*)Ksm + w * 1024;
    char* const vdst = (char*)Vsm + w * 1024;

    float plsum[4] = {0.f, 0.f, 0.f, 0.f};
    f32x4 oacc[4] = {};

    for (int t = 0; t < 8; ++t) {
        gload16(Kh + t * 4096 + goff, kdst);
        gload16(Vh + t * 4096 + goff, vdst);
        __syncthreads();                 // drains vmcnt -> tiles ready

        // ---- QK^T: s[nf] covers kv cols nf*16+colw, q rows grp*4+r ----
        f32x4 s[4] = {};
        #pragma unroll
        for (int ks = 0; ks < 2; ++ks) {
            #pragma unroll
            for (int nf = 0; nf < 4; ++nf) {
                const int rowb = nf * 16 + colw;
                const short8 bk = *(const short8*)((char*)Ksm + rowb * 128 +
                                       ((((ks * 4 + grp) ^ (rowb & 7))) << 4));
                s[nf] = __builtin_amdgcn_mfma_f32_16x16x32_bf16(aq[ks], bk, s[nf], 0, 0, 0);
            }
        }
        // ---- p = exp(s), accumulate row sums, write P to per-wave LDS ----
        #pragma unroll
        for (int nf = 0; nf < 4; ++nf) {
            #pragma unroll
            for (int r = 0; r < 4; ++r) {
                const float p = __expf(s[nf][r]);
                plsum[r] += p;
                Psm[w][(grp * 4 + r) * 72 + nf * 16 + colw] = f2bf(p);
            }
        }
        // ---- PV: A = P (k=kv), B = V_lds (rows=d, k=kv) ----
        #pragma unroll
        for (int ks2 = 0; ks2 < 2; ++ks2) {
            const short8 ap = *(const short8*)&Psm[w][colw * 72 + ks2 * 32 + grp * 8];
            #pragma unroll
            for (int nf = 0; nf < 4; ++nf) {
                const int rowv = nf * 16 + colw;
                const short8 bv = *(const short8*)((char*)Vsm + rowv * 128 +
                                       ((((ks2 * 4 + grp) ^ (rowv & 7))) << 4));
                oacc[nf] = __builtin_amdgcn_mfma_f32_16x16x32_bf16(ap, bv, oacc[nf], 0, 0, 0);
            }
        }
        __syncthreads();                 // protect LDS tiles before restage
    }

    // single cross-lane reduce of the row sums (16-lane groups)
    float oinv[4];
    #pragma unroll
    for (int r = 0; r < 4; ++r) {
        float t = plsum[r];
        t += __shfl_xor(t, 1);
        t += __shfl_xor(t, 2);
        t += __shfl_xor(t, 4);
        t += __shfl_xor(t, 8);
        oinv[r] = 1.0f / t;
    }

    const int bt = bth >> 4, h = bth & 15;
    #pragma unroll
    for (int nf = 0; nf < 4; ++nf) {
        #pragma unroll
        for (int r = 0; r < 4; ++r) {
            const int i = bt * LSEQ + q0 + grp * 4 + r;
            const int c = h * 64 + nf * 16 + colw;
            Ob[(size_t)i * CD + c] = f2bf(oacc[nf][r] * oinv[r]);
        }
    }
}

// ---------------- Kernel 3: output projection + bias + residual ----------
__global__ __launch_bounds__(512, 2)
void proj_out_kernel(const unsigned short* __restrict__ Ob,
                     const unsigned short* __restrict__ wmb,
                     const float* __restrict__ bm,
                     const float* __restrict__ x, float* __restrict__ out)
{
    __shared__ __attribute__((aligned(16))) char lds[96 * 1024];

    // grid = 256 (64 m-tiles x 4 n-tiles), bijective XCD swizzle
    const int wg   = (blockIdx.x & 7) * 32 + (blockIdx.x >> 3);
    const int in_t = wg >> 6, im_t = wg & 63;
    const int i0 = im_t * 128, n0 = in_t * 256;

    const int tid  = threadIdx.x;
    const int w    = tid >> 6;
    const int lane = tid & 63;
    const int colw = lane & 15;
    const int grp  = lane >> 4;
    const int wm   = w >> 2, wn = w & 3;

    f32x4 acc[4][4] = {};
    gemm_core(Ob, wmb, i0, n0, lds, acc);

    #pragma unroll
    for (int nf = 0; nf < 4; ++nf) {
        const int j = n0 + wn * 64 + nf * 16 + colw;
        const float bv = bm[j];
        #pragma unroll
        for (int mf = 0; mf < 4; ++mf) {
            #pragma unroll
            for (int r = 0; r < 4; ++r) {
                const int i = i0 + wm * 64 + mf * 16 + grp * 4 + r;
                out[(size_t)i * CD + j] = acc[mf][nf][r] + bv + x[(size_t)i * CD + j];
            }
        }
    }
}

extern "C" void kernel_launch(void* const* d_in, const int* in_sizes, int n_in,
                              void* d_out, int out_size, void* d_ws, size_t ws_size,
                              hipStream_t stream) {
    const float* x   = (const float*)d_in[0];
    const float* wq  = (const float*)d_in[1];
    const float* bq  = (const float*)d_in[2];
    const float* wkv = (const float*)d_in[3];
    const float* bkv = (const float*)d_in[4];
    const float* wm  = (const float*)d_in[5];
    const float* bm  = (const float*)d_in[6];
    float* out = (float*)d_out;

    // ws layout (64 MB, timeline-aliased):
    //  R0: xb (convert->proj_qkv), then Ob (attn->proj_out)
    //  R1: Qb (proj_qkv->attn), then wmb (cvt-after-attn->proj_out)
    //  R2: Kb   R3: Vtb
    // wqkvb lives in d_out (dead before proj_out writes it).
    const size_t SEG = (size_t)MROWS * CD;
    unsigned short* xb    = (unsigned short*)d_ws;
    unsigned short* Ob    = xb;
    unsigned short* Qb    = xb + SEG;
    unsigned short* wmb   = Qb;
    unsigned short* Kb    = Qb + SEG;
    unsigned short* Vtb   = Kb + SEG;
    unsigned short* wqkvb = (unsigned short*)d_out;

    cvt_kernel<<<2048, 256, 0, stream>>>(x,   xb,    (MROWS * CD) / 4);
    cvt_kernel<<<1024, 256, 0, stream>>>(wq,  wqkvb, (CD * CD) / 4);
    cvt_kernel<<<1024, 256, 0, stream>>>(wkv, wqkvb + (size_t)CD * CD, (2 * CD * CD) / 4);
    proj_qkv_kernel<<<768, 512, 0, stream>>>(xb, wqkvb, bq, bkv, Qb, Kb, Vtb);
    attn_kernel<<<1024, 512, 0, stream>>>(Qb, Kb, Vtb, Ob);
    cvt_kernel<<<1024, 256, 0, stream>>>(wm, wmb, (CD * CD) / 4);
    proj_out_kernel<<<256, 512, 0, stream>>>(Ob, wmb, bm, x, out);
}

// Round 6
// 171.937 us; speedup vs baseline: 1.9437x; 1.0799x over previous
//
#include <hip/hip_runtime.h>
#include <hip/hip_bf16.h>

typedef __attribute__((ext_vector_type(8))) short short8;
typedef __attribute__((ext_vector_type(4))) float f32x4;

#define HEADS 16
#define DH    64
#define LSEQ  512
#define CD    1024
#define MROWS 8192            /* B*T*L */

static __device__ __forceinline__ unsigned short f2bf(float f) {
    union { float f; unsigned int u; } v; v.f = f;
    unsigned int u = v.u;
    u += 0x7fffu + ((u >> 16) & 1u);   // round-to-nearest-even
    return (unsigned short)(u >> 16);
}

static __device__ __forceinline__ void gload16(const unsigned short* g, char* lds) {
    __builtin_amdgcn_global_load_lds(
        (const __attribute__((address_space(1))) void*)g,
        (__attribute__((address_space(3))) void*)lds, 16, 0, 0);
}

// ---------------- f32 -> bf16 bulk convert (vec4) ----------------
__global__ __launch_bounds__(256)
void cvt_kernel(const float* __restrict__ s, unsigned short* __restrict__ d, int n4) {
    union U { unsigned short us[4]; unsigned long long u; };
    for (int i = blockIdx.x * blockDim.x + threadIdx.x; i < n4; i += gridDim.x * blockDim.x) {
        const float4 v = ((const float4*)s)[i];
        U p; p.us[0] = f2bf(v.x); p.us[1] = f2bf(v.y); p.us[2] = f2bf(v.z); p.us[3] = f2bf(v.w);
        ((unsigned long long*)d)[i] = p.u;
    }
}

// ================= m97-structure GEMM core =================
// BM=BN=128, BK=64, 4 waves (2x2), single 32KB LDS buffer, 2 barriers/K-step,
// global_load_lds width-16, both-sides XOR chunk swizzle (chunk ^= row&7).
// Latency hiding comes from multi-block occupancy (~3 blocks/CU), not from
// source-level pipelining (compiler drains LDS-DMA before aliasing ds_reads).
static __device__ __forceinline__ void gemm128_core(
    const unsigned short* __restrict__ Ap,   // [M][CD] bf16, row-major
    const unsigned short* __restrict__ Bp,   // [N][CD] bf16, row-major
    int i0, int n0, unsigned short* Asm, unsigned short* Bsm, f32x4 acc[4][4])
{
    const int tid  = threadIdx.x;
    const int wv   = tid >> 6;        // 0..3
    const int lane = tid & 63;
    const int colw = lane & 15;
    const int grp  = lane >> 4;
    const int wr   = wv >> 1;         // row half
    const int wc   = wv & 1;          // col half

    // staging: per instr, wave covers 8 rows x 128B (dense); LDS dest linear.
    // global chunk pre-swizzled so LDS phys chunk p holds logical p^(row&7).
    const int srow0 = lane >> 3;                 // 0..7 row within 8-row chunk
    const int sclog = (lane & 7) ^ (srow0 & 7);  // row&7 == srow0&7 for +8-multiples
    char* const adst = (char*)Asm + wv * 32 * 128;
    char* const bdst = (char*)Bsm + wv * 32 * 128;

    // ds_read byte offsets (swizzled): row*128 + ((ks*4+grp)^(row&7))*16
    int aoff[2][4], boff[2][4];
    #pragma unroll
    for (int ks = 0; ks < 2; ++ks) {
        #pragma unroll
        for (int f = 0; f < 4; ++f) {
            const int ra = wr * 64 + f * 16 + colw;
            const int rb = wc * 64 + f * 16 + colw;
            aoff[ks][f] = ra * 128 + (((ks * 4 + grp) ^ (ra & 7)) << 4);
            boff[ks][f] = rb * 128 + (((ks * 4 + grp) ^ (rb & 7)) << 4);
        }
    }

    for (int kt = 0; kt < CD; kt += 64) {
        #pragma unroll
        for (int c = 0; c < 4; ++c) {
            const int row = wv * 32 + c * 8 + srow0;
            gload16(Ap + (size_t)(i0 + row) * CD + kt + sclog * 8, adst + c * 1024);
            gload16(Bp + (size_t)(n0 + row) * CD + kt + sclog * 8, bdst + c * 1024);
        }
        __syncthreads();   // compiler drains vmcnt here; hidden by co-resident blocks
        #pragma unroll
        for (int ks = 0; ks < 2; ++ks) {
            short8 af[4], bf[4];
            #pragma unroll
            for (int f = 0; f < 4; ++f) af[f] = *(const short8*)((char*)Asm + aoff[ks][f]);
            #pragma unroll
            for (int f = 0; f < 4; ++f) bf[f] = *(const short8*)((char*)Bsm + boff[ks][f]);
            #pragma unroll
            for (int mf = 0; mf < 4; ++mf)
                #pragma unroll
                for (int nf = 0; nf < 4; ++nf)
                    acc[mf][nf] = __builtin_amdgcn_mfma_f32_16x16x32_bf16(af[mf], bf[nf], acc[mf][nf], 0, 0, 0);
        }
        __syncthreads();   // reads done before next stage overwrites
    }
}

// ---------------- Kernel 1: fused QKV projection ----------
__global__ __launch_bounds__(256)
void proj_qkv_kernel(const unsigned short* __restrict__ xb,
                     const unsigned short* __restrict__ wqkvb,
                     const float* __restrict__ bq, const float* __restrict__ bkv,
                     unsigned short* __restrict__ Qb, unsigned short* __restrict__ Kb,
                     unsigned short* __restrict__ Vtb)
{
    __shared__ __attribute__((aligned(16))) unsigned short Asm[128 * 64];
    __shared__ __attribute__((aligned(16))) unsigned short Bsm[128 * 64];

    // grid = 1536 (64 m x 24 n); bijective XCD swizzle; B-panel reuse per XCD
    const int xcd = blockIdx.x & 7, wgl = blockIdx.x >> 3;   // wgl 0..191
    const int im  = xcd * 8 + wgl / 24;
    const int in  = wgl % 24;
    const int i0 = im * 128, j0 = in * 128;

    const int tid  = threadIdx.x;
    const int wv   = tid >> 6;
    const int lane = tid & 63;
    const int colw = lane & 15;
    const int grp  = lane >> 4;
    const int wr   = wv >> 1, wc = wv & 1;

    f32x4 acc[4][4] = {};
    gemm128_core(xb, wqkvb, i0, j0, Asm, Bsm, acc);

    // ---- epilogue: bias + l2norm over 64-col head; scatter store ----
    const int jbase = j0 + wc * 64;               // head-aligned, wave-uniform
    const float* bp = (jbase < CD) ? (bq + jbase) : (bkv + (jbase - CD));
    #pragma unroll
    for (int nf = 0; nf < 4; ++nf) {
        const float bv = bp[nf * 16 + colw];
        #pragma unroll
        for (int mf = 0; mf < 4; ++mf)
            #pragma unroll
            for (int r = 0; r < 4; ++r) acc[mf][nf][r] += bv;
    }
    const float qscale = (jbase < CD) ? 0.125f : 1.0f;
    float inv[4][4];
    #pragma unroll
    for (int mf = 0; mf < 4; ++mf) {
        #pragma unroll
        for (int r = 0; r < 4; ++r) {
            float t = 0.f;
            #pragma unroll
            for (int nf = 0; nf < 4; ++nf) t += acc[mf][nf][r] * acc[mf][nf][r];
            t += __shfl_xor(t, 1);
            t += __shfl_xor(t, 2);
            t += __shfl_xor(t, 4);
            t += __shfl_xor(t, 8);
            inv[mf][r] = qscale / fmaxf(sqrtf(t), 1e-12f);
        }
    }
    // wave-uniform destination select
    unsigned short* dst; int jloc;
    if (jbase < CD)            { dst = Qb;  jloc = jbase; }
    else if (jbase < 2 * CD)   { dst = Kb;  jloc = jbase - CD; }
    else                       { dst = Vtb; jloc = jbase - 2 * CD; }
    const int h = jloc >> 6;
    #pragma unroll
    for (int mf = 0; mf < 4; ++mf) {
        #pragma unroll
        for (int nf = 0; nf < 4; ++nf) {
            const int d = nf * 16 + colw;
            #pragma unroll
            for (int r = 0; r < 4; ++r) {
                const int i  = i0 + wr * 64 + mf * 16 + grp * 4 + r;
                const int bt = i >> 9, li = i & 511;
                const unsigned short hv = f2bf(acc[mf][nf][r] * inv[mf][r]);
                if (jbase < 2 * CD)
                    dst[(((size_t)(bt * HEADS + h)) * LSEQ + li) * DH + d] = hv;     // Q or K [l][d]
                else
                    // V tiled: [bth][l/64][d][64] -> contiguous 8KB kv-tiles for attn
                    dst[((((size_t)(bt * HEADS + h)) * 8 + (li >> 6)) * DH + d) * 64 + (li & 63)] = hv;
            }
        }
    }
}

// ---------------- Kernel 2: flash attention per (b,t,h) ----------
// Bounded-score softmax (|s|<=0.125): exp(s) directly, no max tracking.
// 8 waves x 16 q-rows = 128 q/block; K/V kv-tiles (64x64, contiguous 8KB)
// staged in LDS once per block via global_load_lds, XOR-swizzled both sides.
__global__ __launch_bounds__(512)
void attn_kernel(const unsigned short* __restrict__ Qb,
                 const unsigned short* __restrict__ Kb,
                 const unsigned short* __restrict__ Vtb,   // tiled [bth][8][64][64]
                 unsigned short* __restrict__ Ob)
{
    __shared__ __attribute__((aligned(16))) unsigned short Ksm[64 * 64];
    __shared__ __attribute__((aligned(16))) unsigned short Vsm[64 * 64];
    __shared__ __attribute__((aligned(16))) unsigned short Psm[8][16 * 72];

    const int tid  = threadIdx.x;
    const int w    = tid >> 6;        // 0..7
    const int lane = tid & 63;
    const int colw = lane & 15;
    const int grp  = lane >> 4;

    const int bth = blockIdx.x & 255;     // head id (same XCD for all its q-tiles)
    const int qt  = blockIdx.x >> 8;      // 0..3
    const int q0  = qt * 128 + w * 16;    // wave's first q row

    const unsigned short* Qh = Qb  + (size_t)bth * LSEQ * DH;
    const unsigned short* Kh = Kb  + (size_t)bth * LSEQ * DH;
    const unsigned short* Vh = Vtb + (size_t)bth * LSEQ * DH;  // tiled

    short8 aq[2];
    #pragma unroll
    for (int ks = 0; ks < 2; ++ks)
        aq[ks] = *(const short8*)&Qh[(size_t)(q0 + colw) * DH + ks * 32 + grp * 8];

    // staging source (pre-swizzled): LDS linear dest = wave base + lane*16
    const int srow   = w * 8 + (lane >> 3);          // 0..63
    const int schunk = (lane & 7) ^ (srow & 7);      // swizzled 16B chunk
    const int goff   = srow * DH + schunk * 8;       // element offset in 8KB tile
    char* const kdst = (char*)Ksm + w * 1024;
    char* const vdst = (char*)Vsm + w * 1024;

    float plsum[4] = {0.f, 0.f, 0.f, 0.f};
    f32x4 oacc[4] = {};

    for (int t = 0; t < 8; ++t) {
        gload16(Kh + t * 4096 + goff, kdst);
        gload16(Vh + t * 4096 + goff, vdst);
        __syncthreads();                 // drains vmcnt -> tiles ready

        // ---- QK^T: s[nf] covers kv cols nf*16+colw, q rows grp*4+r ----
        f32x4 s[4] = {};
        #pragma unroll
        for (int ks = 0; ks < 2; ++ks) {
            #pragma unroll
            for (int nf = 0; nf < 4; ++nf) {
                const int rowb = nf * 16 + colw;
                const short8 bk = *(const short8*)((char*)Ksm + rowb * 128 +
                                       ((((ks * 4 + grp) ^ (rowb & 7))) << 4));
                s[nf] = __builtin_amdgcn_mfma_f32_16x16x32_bf16(aq[ks], bk, s[nf], 0, 0, 0);
            }
        }
        // ---- p = exp(s), accumulate row sums, write P to per-wave LDS ----
        #pragma unroll
        for (int nf = 0; nf < 4; ++nf) {
            #pragma unroll
            for (int r = 0; r < 4; ++r) {
                const float p = __expf(s[nf][r]);
                plsum[r] += p;
                Psm[w][(grp * 4 + r) * 72 + nf * 16 + colw] = f2bf(p);
            }
        }
        // ---- PV: A = P (k=kv), B = V_lds (rows=d, k=kv) ----
        #pragma unroll
        for (int ks2 = 0; ks2 < 2; ++ks2) {
            const short8 ap = *(const short8*)&Psm[w][colw * 72 + ks2 * 32 + grp * 8];
            #pragma unroll
            for (int nf = 0; nf < 4; ++nf) {
                const int rowv = nf * 16 + colw;
                const short8 bv = *(const short8*)((char*)Vsm + rowv * 128 +
                                       ((((ks2 * 4 + grp) ^ (rowv & 7))) << 4));
                oacc[nf] = __builtin_amdgcn_mfma_f32_16x16x32_bf16(ap, bv, oacc[nf], 0, 0, 0);
            }
        }
        __syncthreads();                 // protect LDS tiles before restage
    }

    // single cross-lane reduce of the row sums (16-lane groups)
    float oinv[4];
    #pragma unroll
    for (int r = 0; r < 4; ++r) {
        float t = plsum[r];
        t += __shfl_xor(t, 1);
        t += __shfl_xor(t, 2);
        t += __shfl_xor(t, 4);
        t += __shfl_xor(t, 8);
        oinv[r] = 1.0f / t;
    }

    const int bt = bth >> 4, h = bth & 15;
    #pragma unroll
    for (int nf = 0; nf < 4; ++nf) {
        #pragma unroll
        for (int r = 0; r < 4; ++r) {
            const int i = bt * LSEQ + q0 + grp * 4 + r;
            const int c = h * 64 + nf * 16 + colw;
            Ob[(size_t)i * CD + c] = f2bf(oacc[nf][r] * oinv[r]);
        }
    }
}

// ---------------- Kernel 3: output projection + bias + residual ----------
__global__ __launch_bounds__(256)
void proj_out_kernel(const unsigned short* __restrict__ Ob,
                     const unsigned short* __restrict__ wmb,
                     const float* __restrict__ bm,
                     const float* __restrict__ x, float* __restrict__ out)
{
    __shared__ __attribute__((aligned(16))) unsigned short Asm[128 * 64];
    __shared__ __attribute__((aligned(16))) unsigned short Bsm[128 * 64];

    // grid = 512 (64 m x 8 n); bijective XCD swizzle
    const int xcd = blockIdx.x & 7, wgl = blockIdx.x >> 3;   // wgl 0..63
    const int im  = xcd * 8 + (wgl >> 3);
    const int in  = wgl & 7;
    const int i0 = im * 128, j0 = in * 128;

    const int tid  = threadIdx.x;
    const int wv   = tid >> 6;
    const int lane = tid & 63;
    const int colw = lane & 15;
    const int grp  = lane >> 4;
    const int wr   = wv >> 1, wc = wv & 1;

    f32x4 acc[4][4] = {};
    gemm128_core(Ob, wmb, i0, j0, Asm, Bsm, acc);

    #pragma unroll
    for (int nf = 0; nf < 4; ++nf) {
        const int j = j0 + wc * 64 + nf * 16 + colw;
        const float bv = bm[j];
        #pragma unroll
        for (int mf = 0; mf < 4; ++mf) {
            #pragma unroll
            for (int r = 0; r < 4; ++r) {
                const int i = i0 + wr * 64 + mf * 16 + grp * 4 + r;
                out[(size_t)i * CD + j] = acc[mf][nf][r] + bv + x[(size_t)i * CD + j];
            }
        }
    }
}

extern "C" void kernel_launch(void* const* d_in, const int* in_sizes, int n_in,
                              void* d_out, int out_size, void* d_ws, size_t ws_size,
                              hipStream_t stream) {
    const float* x   = (const float*)d_in[0];
    const float* wq  = (const float*)d_in[1];
    const float* bq  = (const float*)d_in[2];
    const float* wkv = (const float*)d_in[3];
    const float* bkv = (const float*)d_in[4];
    const float* wm  = (const float*)d_in[5];
    const float* bm  = (const float*)d_in[6];
    float* out = (float*)d_out;

    // ws layout (64 MB, timeline-aliased):
    //  R0: xb (convert->proj_qkv), then Ob (attn->proj_out)
    //  R1: Qb (proj_qkv->attn), then wmb (cvt-after-attn->proj_out)
    //  R2: Kb   R3: Vtb
    // wqkvb lives in d_out (dead before proj_out writes it).
    const size_t SEG = (size_t)MROWS * CD;
    unsigned short* xb    = (unsigned short*)d_ws;
    unsigned short* Ob    = xb;
    unsigned short* Qb    = xb + SEG;
    unsigned short* wmb   = Qb;
    unsigned short* Kb    = Qb + SEG;
    unsigned short* Vtb   = Kb + SEG;
    unsigned short* wqkvb = (unsigned short*)d_out;

    cvt_kernel<<<2048, 256, 0, stream>>>(x,   xb,    (MROWS * CD) / 4);
    cvt_kernel<<<1024, 256, 0, stream>>>(wq,  wqkvb, (CD * CD) / 4);
    cvt_kernel<<<1024, 256, 0, stream>>>(wkv, wqkvb + (size_t)CD * CD, (2 * CD * CD) / 4);
    proj_qkv_kernel<<<1536, 256, 0, stream>>>(xb, wqkvb, bq, bkv, Qb, Kb, Vtb);
    attn_kernel<<<1024, 512, 0, stream>>>(Qb, Kb, Vtb, Ob);
    cvt_kernel<<<1024, 256, 0, stream>>>(wm, wmb, (CD * CD) / 4);
    proj_out_kernel<<<512, 256, 0, stream>>>(Ob, wmb, bm, x, out);
}